// Round 1
// baseline (1119.727 us; speedup 1.0000x reference)
//
#include <hip/hip_runtime.h>
#include <hip/hip_bf16.h>
#include <cstdint>
#include <cstddef>

// ---------------------------------------------------------------------------
// EfficientEquilibriumLayer: LN1 -> QKV(elu+1 on Q,K) -> chunked causal linear
// attention -> O-proj + residual -> LN2 -> GELU FFN + residual.
// B=4, N=4096, D=1024, F=64. All GEMMs bf16 MFMA (16x16x32), fp32 accum.
// R1: XOR-swizzled LDS (bank conflicts 2.5e7 -> 0), tanh-GELU epilogue.
// R2: FFN as N-strips over full M (FFN2 1024 blocks, was 512 grid-starved).
// R3: L2-locality block swizzle in eel_gemm.
// R4 (this): replace 128x128 2-barrier GEMM (25% MfmaUtil, 620 TF) with a
//     256x256 deep-pipelined GEMM: BK=32, 4-buffer LDS ring (128 KiB), 8
//     waves, per-phase {ds_read || global_load_lds prefetch || 16 MFMA}
//     with raw s_barrier + counted s_waitcnt vmcnt(8) (never 0 in the main
//     loop -> 2 tiles of loads stay in flight across barriers), setprio(1)
//     around MFMA clusters, conflict-free seg^((row>>1)&3) swizzle applied
//     via pre-swizzled global source (LDS stays gl_lds-linear), bijective
//     XCD chunking with bx-fastest order (weight tile L2-resident per XCD).
//     QKV N=1152 runs as N=1280 with B-row clamp + store guard col<1152.
// ---------------------------------------------------------------------------

typedef __attribute__((ext_vector_type(8))) short short8;
typedef __attribute__((ext_vector_type(4))) short short4v;
typedef __attribute__((ext_vector_type(4))) float floatx4;
typedef __attribute__((ext_vector_type(4))) unsigned short ushort4v;

#define DEV static __device__ __forceinline__

DEV float b2f(unsigned short u) {
    union { unsigned int i; float f; } v; v.i = ((unsigned int)u) << 16; return v.f;
}
DEV unsigned short f2b(float f) {
    union { float f; unsigned int i; } v; v.f = f;
    unsigned int i = v.i;
    unsigned int r = (i + 0x7FFFu + ((i >> 16) & 1u)) >> 16;
    return (unsigned short)r;
}

DEV void gl_lds16(const void* g, void* l) {
    __builtin_amdgcn_global_load_lds((const __attribute__((address_space(1))) void*)g,
                                     (__attribute__((address_space(3))) void*)l, 16, 0, 0);
}

// ---------------------------------------------------------------------------
// Weight prep: fp32 -> bf16, concat q/k/v weights into Wqkv [1152,1024],
// concat biases into bqkv [1152].
// ---------------------------------------------------------------------------
__global__ void eel_prep(const float* __restrict__ qw, const float* __restrict__ kw,
                         const float* __restrict__ vw, const float* __restrict__ ow,
                         const float* __restrict__ f1w, const float* __restrict__ f2w,
                         const float* __restrict__ qb, const float* __restrict__ kb,
                         const float* __restrict__ vb,
                         uint16_t* __restrict__ Wqkv, uint16_t* __restrict__ Wo,
                         uint16_t* __restrict__ W1, uint16_t* __restrict__ W2,
                         float* __restrict__ bqkv)
{
    size_t i = (size_t)blockIdx.x * 256 + threadIdx.x;
    size_t stride = (size_t)gridDim.x * 256;
    for (size_t t = i; t < 1152u * 1024u; t += stride) {
        int r = (int)(t >> 10);
        float v = (r < 64) ? qw[t] : (r < 128) ? kw[t - 65536] : vw[t - 131072];
        Wqkv[t] = f2b(v);
    }
    for (size_t t = i; t < 1048576u; t += stride) Wo[t] = f2b(ow[t]);
    for (size_t t = i; t < 4194304u; t += stride) { W1[t] = f2b(f1w[t]); W2[t] = f2b(f2w[t]); }
    if (i < 1152) bqkv[i] = (i < 64) ? qb[i] : (i < 128) ? kb[i - 64] : vb[i - 128];
}

// ---------------------------------------------------------------------------
// LayerNorm: one block per row (D=1024), fp32 in -> bf16 out.
// ---------------------------------------------------------------------------
__global__ __launch_bounds__(256) void eel_ln(const float* __restrict__ x,
                                              const float* __restrict__ w,
                                              const float* __restrict__ b,
                                              uint16_t* __restrict__ out)
{
    int row = blockIdx.x, tid = threadIdx.x;
    float4 xv = ((const float4*)(x + (size_t)row * 1024))[tid];
    float s  = xv.x + xv.y + xv.z + xv.w;
    float s2 = xv.x*xv.x + xv.y*xv.y + xv.z*xv.z + xv.w*xv.w;
#pragma unroll
    for (int off = 32; off > 0; off >>= 1) {
        s  += __shfl_down(s, off);
        s2 += __shfl_down(s2, off);
    }
    __shared__ float ps[8];
    int wv = tid >> 6;
    if ((tid & 63) == 0) { ps[wv] = s; ps[4 + wv] = s2; }
    __syncthreads();
    float mu  = (ps[0] + ps[1] + ps[2] + ps[3]) * (1.0f / 1024.0f);
    float var = (ps[4] + ps[5] + ps[6] + ps[7]) * (1.0f / 1024.0f) - mu * mu;
    float rs = rsqrtf(var + 1e-5f);
    float4 wv4 = ((const float4*)w)[tid];
    float4 bv4 = ((const float4*)b)[tid];
    ushort4v o;
    o.x = f2b((xv.x - mu) * rs * wv4.x + bv4.x);
    o.y = f2b((xv.y - mu) * rs * wv4.y + bv4.y);
    o.z = f2b((xv.z - mu) * rs * wv4.z + bv4.z);
    o.w = f2b((xv.w - mu) * rs * wv4.w + bv4.w);
    *(ushort4v*)(out + (size_t)row * 1024 + tid * 4) = o;
}

// ---------------------------------------------------------------------------
// GEMM 256x256: C[M,N] = A[M,K] @ B[N,K]^T (+epilogue). bf16 in, fp32 accum.
// 512 threads = 8 waves (2M x 4N), per-wave 128x64 C. BK=32, ring of 4 LDS
// buffers (A/B 16 KiB each -> 128 KiB total). Deep pipeline: tile T+3 staged
// during tile T's two phases (A in phase 1, B in phase 2); boundary wait is
// s_waitcnt vmcnt(8) (tiles T+2,T+3 in flight) -- never 0 in the main loop.
// Swizzle seg' = seg ^ ((row>>1)&3) applied on the global source (LDS linear
// for global_load_lds); frag rows differ by multiples of 16 so the read-side
// XOR is thread-constant -> ds_read_b128 with immediate offsets, 2-way max
// bank aliasing (free).
// Ring-hazard proof: stage of tile T+3 targets buffer (T-1)&3, whose last
// ds_reads complete before that wave's lgkmcnt(0), which precedes tile T-1's
// final s_barrier; the stage issue is after that barrier. Landing of T+3 is
// confirmed by vmcnt(8)+barrier at end of tile T+2 (12 loads out, oldest 4
// = tile T+3's... i.e. 3 boundaries after issue).
// mode 0: out bf16 = acc+bias, cols<128 get elu(x)+1         (QKV proj)
// mode 1: out fp32 = acc+[bias]+res                          (O-proj / FFN2)
// mode 2: out bf16 = gelu_tanh(acc+bias)                     (FFN1)
// bmax: B rows >= bmax read row 0 (finite garbage, never stored);
// nvalid: stores with col >= nvalid skipped. gridDim.x % 8 == 0 required.
// ---------------------------------------------------------------------------
__global__ __launch_bounds__(512, 2) void eel_gemm256(
    const uint16_t* __restrict__ A, int lda,
    const uint16_t* __restrict__ Bm, int ldb, int bmax,
    int K,
    const float* __restrict__ bias,
    const float* __restrict__ res,
    uint16_t* __restrict__ outb, float* __restrict__ outf,
    int ldc, int mode, int nvalid)
{
    __shared__ uint16_t sA[4][8192];   // 4 bufs x [256 rows][32 k] bf16
    __shared__ uint16_t sB[4][8192];
    int tid = threadIdx.x;
    int lane = tid & 63, w = tid >> 6;
    int quad = lane >> 4, l16 = lane & 15;

    // bijective XCD chunking, bx fastest (weight tile L2-resident per XCD)
    int nblk = gridDim.x, qch = nblk >> 3;
    int lin  = blockIdx.x;
    int tile = (lin & 7) * qch + (lin >> 3);
    int bx = tile & 63, by = tile >> 6;    // M=16384 -> 64 x-panels fixed
    int m0 = bx << 8, n0 = by << 8;

    int wr = (w >> 2) * 128;               // wave row base within tile
    int wc = (w & 3) * 64;                 // wave col base within tile
    int rA = wr + l16;                     // + mq*64 + ii*16
    int rB = wc + l16;                     // + j*16

    floatx4 acc[8][4] = {};
    short8 a0, a1, a2, a3, b0, b1, b2, b3;

    // staging addressing: thread t covers rows t>>2 and (t>>2)+128, seg t&3.
    // global source pre-swizzled: gs = seg ^ ((row>>1)&3)  (row+128 same).
    int srow = tid >> 2, sseg = tid & 3;
    int sgs  = sseg ^ ((srow >> 1) & 3);
    const uint16_t* aptr0 = A + (size_t)(m0 + srow) * lda + sgs * 8;
    const uint16_t* aptr1 = A + (size_t)(m0 + srow + 128) * lda + sgs * 8;
    int br0 = n0 + srow;       if (br0 >= bmax) br0 = 0;
    int br1 = n0 + srow + 128; if (br1 >= bmax) br1 = 0;
    const uint16_t* bptr0 = Bm + (size_t)br0 * ldb + sgs * 8;
    const uint16_t* bptr1 = Bm + (size_t)br1 * ldb + sgs * 8;

#define STAGE_A(Tn) do {                                                      \
    gl_lds16(aptr0 + (Tn) * 32, (char*)sA[(Tn) & 3] + tid * 16);              \
    gl_lds16(aptr1 + (Tn) * 32, (char*)sA[(Tn) & 3] + 8192 + tid * 16);       \
} while (0)
#define STAGE_B(Tn) do {                                                      \
    gl_lds16(bptr0 + (Tn) * 32, (char*)sB[(Tn) & 3] + tid * 16);              \
    gl_lds16(bptr1 + (Tn) * 32, (char*)sB[(Tn) & 3] + 8192 + tid * 16);       \
} while (0)
#define NOSTG do { } while (0)
#define FRG(buf, r) (*(const short8*)((const char*)(buf) + (size_t)(r) * 64 + \
                     ((quad ^ (((r) >> 1) & 3)) * 16)))
#define VMW8 do { asm volatile("s_waitcnt vmcnt(8)"); __builtin_amdgcn_sched_barrier(0); } while (0)
#define VMW4 do { asm volatile("s_waitcnt vmcnt(4)"); __builtin_amdgcn_sched_barrier(0); } while (0)
#define VMW0 do { asm volatile("s_waitcnt vmcnt(0)"); __builtin_amdgcn_sched_barrier(0); } while (0)
#define MFMA16(bb) do {                                                                        \
    acc[(bb)+0][0]=__builtin_amdgcn_mfma_f32_16x16x32_bf16(a0,b0,acc[(bb)+0][0],0,0,0);        \
    acc[(bb)+0][1]=__builtin_amdgcn_mfma_f32_16x16x32_bf16(a0,b1,acc[(bb)+0][1],0,0,0);        \
    acc[(bb)+0][2]=__builtin_amdgcn_mfma_f32_16x16x32_bf16(a0,b2,acc[(bb)+0][2],0,0,0);        \
    acc[(bb)+0][3]=__builtin_amdgcn_mfma_f32_16x16x32_bf16(a0,b3,acc[(bb)+0][3],0,0,0);        \
    acc[(bb)+1][0]=__builtin_amdgcn_mfma_f32_16x16x32_bf16(a1,b0,acc[(bb)+1][0],0,0,0);        \
    acc[(bb)+1][1]=__builtin_amdgcn_mfma_f32_16x16x32_bf16(a1,b1,acc[(bb)+1][1],0,0,0);        \
    acc[(bb)+1][2]=__builtin_amdgcn_mfma_f32_16x16x32_bf16(a1,b2,acc[(bb)+1][2],0,0,0);        \
    acc[(bb)+1][3]=__builtin_amdgcn_mfma_f32_16x16x32_bf16(a1,b3,acc[(bb)+1][3],0,0,0);        \
    acc[(bb)+2][0]=__builtin_amdgcn_mfma_f32_16x16x32_bf16(a2,b0,acc[(bb)+2][0],0,0,0);        \
    acc[(bb)+2][1]=__builtin_amdgcn_mfma_f32_16x16x32_bf16(a2,b1,acc[(bb)+2][1],0,0,0);        \
    acc[(bb)+2][2]=__builtin_amdgcn_mfma_f32_16x16x32_bf16(a2,b2,acc[(bb)+2][2],0,0,0);        \
    acc[(bb)+2][3]=__builtin_amdgcn_mfma_f32_16x16x32_bf16(a2,b3,acc[(bb)+2][3],0,0,0);        \
    acc[(bb)+3][0]=__builtin_amdgcn_mfma_f32_16x16x32_bf16(a3,b0,acc[(bb)+3][0],0,0,0);        \
    acc[(bb)+3][1]=__builtin_amdgcn_mfma_f32_16x16x32_bf16(a3,b1,acc[(bb)+3][1],0,0,0);        \
    acc[(bb)+3][2]=__builtin_amdgcn_mfma_f32_16x16x32_bf16(a3,b2,acc[(bb)+3][2],0,0,0);        \
    acc[(bb)+3][3]=__builtin_amdgcn_mfma_f32_16x16x32_bf16(a3,b3,acc[(bb)+3][3],0,0,0);        \
} while (0)
#define PHASE1(bi, STG) do {                                                  \
    const uint16_t* Ab_ = sA[bi]; const uint16_t* Bb_ = sB[bi];               \
    a0 = FRG(Ab_, rA +  0); a1 = FRG(Ab_, rA + 16);                           \
    a2 = FRG(Ab_, rA + 32); a3 = FRG(Ab_, rA + 48);                           \
    b0 = FRG(Bb_, rB +  0); b1 = FRG(Bb_, rB + 16);                           \
    b2 = FRG(Bb_, rB + 32); b3 = FRG(Bb_, rB + 48);                           \
    STG;                                                                      \
    __builtin_amdgcn_s_barrier();                                             \
    asm volatile("s_waitcnt lgkmcnt(0)");                                     \
    __builtin_amdgcn_sched_barrier(0);                                        \
    __builtin_amdgcn_s_setprio(1);                                            \
    MFMA16(0);                                                                \
    __builtin_amdgcn_s_setprio(0);                                            \
    __builtin_amdgcn_s_barrier();                                             \
} while (0)
#define PHASE2(bi, STG, VM) do {                                              \
    const uint16_t* Ab_ = sA[bi];                                             \
    a0 = FRG(Ab_, rA + 64); a1 = FRG(Ab_, rA + 80);                           \
    a2 = FRG(Ab_, rA + 96); a3 = FRG(Ab_, rA + 112);                          \
    STG;                                                                      \
    __builtin_amdgcn_s_barrier();                                             \
    asm volatile("s_waitcnt lgkmcnt(0)");                                     \
    __builtin_amdgcn_sched_barrier(0);                                        \
    __builtin_amdgcn_s_setprio(1);                                            \
    MFMA16(4);                                                                \
    __builtin_amdgcn_s_setprio(0);                                            \
    VM;                                                                       \
    __builtin_amdgcn_s_barrier();                                             \
} while (0)

    // prologue: stage tiles 0,1,2 (12 loads/thread); confirm tile 0, keep 8
    // loads (tiles 1,2) in flight.
    STAGE_A(0); STAGE_B(0);
    STAGE_A(1); STAGE_B(1);
    STAGE_A(2); STAGE_B(2);
    asm volatile("s_waitcnt vmcnt(8)");
    __builtin_amdgcn_sched_barrier(0);
    __builtin_amdgcn_s_barrier();

    int nT = K >> 5;
    int T = 0;
    for (; T < nT - 3; ++T) {
        int bi = T & 3;
        PHASE1(bi, STAGE_A(T + 3));
        PHASE2(bi, STAGE_B(T + 3), VMW8);
    }
    PHASE1(T & 3, NOSTG); PHASE2(T & 3, NOSTG, VMW4); ++T;
    PHASE1(T & 3, NOSTG); PHASE2(T & 3, NOSTG, VMW0); ++T;
    PHASE1(T & 3, NOSTG); PHASE2(T & 3, NOSTG, NOSTG);

    // epilogue
#pragma unroll
    for (int j = 0; j < 4; j++) {
        int col = n0 + wc + j * 16 + l16;
        if (col < nvalid) {
            float bv = bias ? bias[col] : 0.0f;
#pragma unroll
            for (int i = 0; i < 8; i++) {
#pragma unroll
                for (int r2 = 0; r2 < 4; r2++) {
                    int row = m0 + wr + i * 16 + quad * 4 + r2;
                    float v = acc[i][j][r2] + bv;
                    size_t off = (size_t)row * ldc + col;
                    if (mode == 0) {
                        if (col < 128) v = (v > 0.f) ? v + 1.f : __expf(v);
                        outb[off] = f2b(v);
                    } else if (mode == 1) {
                        outf[off] = v + res[off];
                    } else {
                        // gelu tanh-approx; tanh(u) = 1 - 2/(exp(2u)+1), inf-safe
                        float u = 0.7978845608028654f * v * (1.0f + 0.044715f * v * v);
                        float e = __expf(2.0f * u);
                        float t = 1.0f - 2.0f / (e + 1.0f);
                        v = 0.5f * v * (1.0f + t);
                        outb[off] = f2b(v);
                    }
                }
            }
        }
    }
#undef STAGE_A
#undef STAGE_B
#undef NOSTG
#undef FRG
#undef VMW8
#undef VMW4
#undef VMW0
#undef MFMA16
#undef PHASE1
#undef PHASE2
}

// ---------------------------------------------------------------------------
// Attention phase A1: per chunk (64 tokens) compute S = causal(Q K^T) (bf16),
// den_intra[n] = rowsum(S), Ks_c[f] = colsum(K). One block per chunk.
// QKV layout: [16384][1152] bf16, Q at col 0, K at 64, V at 128.
// ---------------------------------------------------------------------------
__global__ __launch_bounds__(256) void eel_attn_s(
    const uint16_t* __restrict__ QKV,
    uint16_t* __restrict__ Sg,      // [16384][64]
    float* __restrict__ den,        // [16384]
    float* __restrict__ KsA)        // [256][64]
{
    int chunk = blockIdx.x, tid = threadIdx.x;
    int tok0 = chunk * 64;
    __shared__ uint16_t Q[64 * 64];
    __shared__ uint16_t Kc[64 * 64];
    __shared__ float denp[64][4];
    {
        int nloc = tid >> 2, seg = tid & 3;
        const uint16_t* src = QKV + (size_t)(tok0 + nloc) * 1152 + seg * 16;
        *(short8*)(Q + nloc * 64 + seg * 16)     = *(const short8*)(src);
        *(short8*)(Q + nloc * 64 + seg * 16 + 8) = *(const short8*)(src + 8);
        src += 64;
        *(short8*)(Kc + nloc * 64 + seg * 16)     = *(const short8*)(src);
        *(short8*)(Kc + nloc * 64 + seg * 16 + 8) = *(const short8*)(src + 8);
    }
    __syncthreads();
    if (tid < 64) {
        float s = 0.f;
        for (int m = 0; m < 64; m++) s += b2f(Kc[m * 64 + tid]);
        KsA[chunk * 64 + tid] = s;
    }
    int n = tid >> 2, mg = tid & 3;
    float dsum = 0.f;
    for (int mi = 0; mi < 16; mi++) {
        int m = mg * 16 + mi;
        size_t soff = (size_t)(tok0 + n) * 64 + m;
        if (m <= n) {
            float s = 0.f;
#pragma unroll
            for (int f = 0; f < 64; f += 8) {
                short8 q8 = *(const short8*)(Q + n * 64 + f);
                short8 k8 = *(const short8*)(Kc + m * 64 + f);
#pragma unroll
                for (int j = 0; j < 8; j++)
                    s += b2f((unsigned short)q8[j]) * b2f((unsigned short)k8[j]);
            }
            dsum += s;
            Sg[soff] = f2b(s);
        } else {
            Sg[soff] = 0;
        }
    }
    denp[n][mg] = dsum;
    __syncthreads();
    if (tid < 64)
        den[tok0 + tid] = denp[tid][0] + denp[tid][1] + denp[tid][2] + denp[tid][3];
}

// ---------------------------------------------------------------------------
// Attention phase A2: per (chunk, d-panel of 128) compute KV_c[f, d] = K^T V.
// Output bf16 [256 chunks][64 f][1024 d].
// ---------------------------------------------------------------------------
__global__ __launch_bounds__(256) void eel_attn_kv(
    const uint16_t* __restrict__ QKV,
    uint16_t* __restrict__ KV_A)
{
    int bi = blockIdx.x;
    int chunk = bi >> 3, p = bi & 7;
    int tid = threadIdx.x;
    int tok0 = chunk * 64;
    __shared__ uint16_t Kc[64 * 64];
    __shared__ uint16_t Vp[64 * 128];
    {
        int r = tid >> 2, sg = tid & 3;
        const uint16_t* src = QKV + (size_t)(tok0 + r) * 1152 + 64 + sg * 16;
        *(short8*)(Kc + r * 64 + sg * 16)     = *(const short8*)(src);
        *(short8*)(Kc + r * 64 + sg * 16 + 8) = *(const short8*)(src + 8);
    }
#pragma unroll
    for (int it = 0; it < 2; it++) {
        int s = it * 256 + tid;
        int r = s >> 3, sub = s & 7;
        const uint16_t* src = QKV + (size_t)(tok0 + r) * 1152 + 128 + p * 128 + sub * 16;
        *(short8*)(Vp + r * 128 + sub * 16)     = *(const short8*)(src);
        *(short8*)(Vp + r * 128 + sub * 16 + 8) = *(const short8*)(src + 8);
    }
    __syncthreads();
    int f0 = (tid >> 5) * 8, d0 = (tid & 31) * 4;
    float acc[8][4] = {};
#pragma unroll 2
    for (int m = 0; m < 64; m++) {
        short8 k8 = *(const short8*)(Kc + m * 64 + f0);
        short4v v4 = *(const short4v*)(Vp + m * 128 + d0);
        float v0 = b2f((unsigned short)v4[0]), v1 = b2f((unsigned short)v4[1]);
        float v2 = b2f((unsigned short)v4[2]), v3 = b2f((unsigned short)v4[3]);
#pragma unroll
        for (int i = 0; i < 8; i++) {
            float kk = b2f((unsigned short)k8[i]);
            acc[i][0] += kk * v0; acc[i][1] += kk * v1;
            acc[i][2] += kk * v2; acc[i][3] += kk * v3;
        }
    }
#pragma unroll
    for (int i = 0; i < 8; i++) {
        ushort4v st;
        st.x = f2b(acc[i][0]); st.y = f2b(acc[i][1]);
        st.z = f2b(acc[i][2]); st.w = f2b(acc[i][3]);
        *(ushort4v*)(KV_A + ((size_t)chunk * 64 + f0 + i) * 1024 + p * 128 + d0) = st;
    }
}

// ---------------------------------------------------------------------------
// Phase B1: exclusive prefix over 64 chunks per batch of KV states (bf16 in,
// fp32 accum, bf16 out). Grid: 1024 blocks (b*256 + f*4 + dseg), 256 threads.
// ---------------------------------------------------------------------------
__global__ __launch_bounds__(256) void eel_kv_prefix(
    const uint16_t* __restrict__ KV_A, uint16_t* __restrict__ KV_P)
{
    int bi = blockIdx.x;
    int b = bi >> 8, rem = bi & 255;
    int f = rem >> 2;
    int d = (rem & 3) * 256 + threadIdx.x;
    float acc = 0.f;
    for (int cc = 0; cc < 64; cc++) {
        size_t idx = (((size_t)(b * 64 + cc)) * 64 + f) * 1024 + d;
        KV_P[idx] = f2b(acc);
        acc += b2f(KV_A[idx]);
    }
}

// Phase B2: exclusive prefix of Ks over chunks. Grid 4 x 64 threads.
__global__ void eel_ks_prefix(const float* __restrict__ KsA, float* __restrict__ KsP)
{
    int b = blockIdx.x, f = threadIdx.x;
    float acc = 0.f;
    for (int cc = 0; cc < 64; cc++) {
        int idx = (b * 64 + cc) * 64 + f;
        KsP[idx] = acc;
        acc += KsA[idx];
    }
}

// ---------------------------------------------------------------------------
// Phase C: per (chunk, d-panel) attn[n,d] = (Q·KV_prev + S·V) / den_full.
// ---------------------------------------------------------------------------
__global__ __launch_bounds__(256) void eel_attn_out(
    const uint16_t* __restrict__ QKV,
    const uint16_t* __restrict__ Sg,
    const float* __restrict__ den,
    const float* __restrict__ KsP,
    const uint16_t* __restrict__ KV_P,
    uint16_t* __restrict__ attn)    // [16384][1024] bf16
{
    int bi = blockIdx.x;
    int chunk = bi >> 3, p = bi & 7;
    int tid = threadIdx.x;
    int tok0 = chunk * 64;
    __shared__ uint16_t Qt[64 * 64];    // [f][n]
    __shared__ uint16_t St[64 * 64];    // [m][n]
    __shared__ uint16_t Vp[64 * 128];   // [m][d]
    __shared__ uint16_t KVp[64 * 128];  // [f][d]
    __shared__ float dfull[64];
    {
        int n = tid >> 2, fs = (tid & 3) * 16;
        const uint16_t* qsrc = QKV + (size_t)(tok0 + n) * 1152 + fs;
        short8 a0 = *(const short8*)(qsrc);
        short8 a1 = *(const short8*)(qsrc + 8);
        const uint16_t* ssrc = Sg + (size_t)(tok0 + n) * 64 + fs;
        short8 s0 = *(const short8*)(ssrc);
        short8 s1 = *(const short8*)(ssrc + 8);
#pragma unroll
        for (int j = 0; j < 8; j++) {
            Qt[(fs + j) * 64 + n]     = (unsigned short)a0[j];
            Qt[(fs + 8 + j) * 64 + n] = (unsigned short)a1[j];
            St[(fs + j) * 64 + n]     = (unsigned short)s0[j];
            St[(fs + 8 + j) * 64 + n] = (unsigned short)s1[j];
        }
    }
#pragma unroll
    for (int it = 0; it < 2; it++) {
        int s = it * 256 + tid;
        int r = s >> 3, sub = s & 7;
        const uint16_t* vsrc = QKV + (size_t)(tok0 + r) * 1152 + 128 + p * 128 + sub * 16;
        *(short8*)(Vp + r * 128 + sub * 16)     = *(const short8*)(vsrc);
        *(short8*)(Vp + r * 128 + sub * 16 + 8) = *(const short8*)(vsrc + 8);
        const uint16_t* kvsrc = KV_P + ((size_t)(chunk * 64 + r)) * 1024 + p * 128 + sub * 16;
        *(short8*)(KVp + r * 128 + sub * 16)     = *(const short8*)(kvsrc);
        *(short8*)(KVp + r * 128 + sub * 16 + 8) = *(const short8*)(kvsrc + 8);
    }
    __syncthreads();
    if (tid < 64) {
        float s = 0.f;
        for (int f = 0; f < 64; f++)
            s += b2f(Qt[f * 64 + tid]) * KsP[chunk * 64 + f];
        dfull[tid] = s + den[tok0 + tid] + 1e-6f;
    }
    __syncthreads();
    int n0 = (tid >> 5) * 8, d0 = (tid & 31) * 4;
    float acc[8][4] = {};
#pragma unroll 2
    for (int f = 0; f < 64; f++) {
        short8 q8 = *(const short8*)(Qt + f * 64 + n0);
        short4v kv4 = *(const short4v*)(KVp + f * 128 + d0);
        float v0 = b2f((unsigned short)kv4[0]), v1 = b2f((unsigned short)kv4[1]);
        float v2 = b2f((unsigned short)kv4[2]), v3 = b2f((unsigned short)kv4[3]);
#pragma unroll
        for (int i = 0; i < 8; i++) {
            float q = b2f((unsigned short)q8[i]);
            acc[i][0] += q * v0; acc[i][1] += q * v1;
            acc[i][2] += q * v2; acc[i][3] += q * v3;
        }
    }
#pragma unroll 2
    for (int m = 0; m < 64; m++) {
        short8 s8 = *(const short8*)(St + m * 64 + n0);
        short4v v4 = *(const short4v*)(Vp + m * 128 + d0);
        float v0 = b2f((unsigned short)v4[0]), v1 = b2f((unsigned short)v4[1]);
        float v2 = b2f((unsigned short)v4[2]), v3 = b2f((unsigned short)v4[3]);
#pragma unroll
        for (int i = 0; i < 8; i++) {
            float q = b2f((unsigned short)s8[i]);
            acc[i][0] += q * v0; acc[i][1] += q * v1;
            acc[i][2] += q * v2; acc[i][3] += q * v3;
        }
    }
#pragma unroll
    for (int i = 0; i < 8; i++) {
        int n = n0 + i;
        float rinv = 1.0f / dfull[n];
        ushort4v st;
        st.x = f2b(acc[i][0] * rinv);
        st.y = f2b(acc[i][1] * rinv);
        st.z = f2b(acc[i][2] * rinv);
        st.w = f2b(acc[i][3] * rinv);
        *(ushort4v*)(attn + (size_t)(tok0 + n) * 1024 + p * 128 + d0) = st;
    }
}

// ---------------------------------------------------------------------------
// Host launcher
// ---------------------------------------------------------------------------
extern "C" void kernel_launch(void* const* d_in, const int* in_sizes, int n_in,
                              void* d_out, int out_size, void* d_ws, size_t ws_size,
                              hipStream_t stream)
{
    (void)in_sizes; (void)n_in; (void)out_size; (void)ws_size;
    const float* x     = (const float*)d_in[0];
    const float* ln1w  = (const float*)d_in[1];
    const float* ln1b  = (const float*)d_in[2];
    const float* qw    = (const float*)d_in[3];
    const float* qb    = (const float*)d_in[4];
    const float* kw    = (const float*)d_in[5];
    const float* kb    = (const float*)d_in[6];
    const float* vw    = (const float*)d_in[7];
    const float* vb    = (const float*)d_in[8];
    const float* ow    = (const float*)d_in[9];
    const float* ob    = (const float*)d_in[10];
    const float* ln2w  = (const float*)d_in[11];
    const float* ln2b  = (const float*)d_in[12];
    const float* f1w   = (const float*)d_in[13];
    const float* f1b   = (const float*)d_in[14];
    const float* f2w   = (const float*)d_in[15];
    const float* f2bs  = (const float*)d_in[16];
    float* out = (float*)d_out;
    char* ws = (char*)d_ws;

    // workspace layout (bytes)
    const size_t o_Wqkv = 0;                              // 1152*1024*2
    const size_t o_Wo   = o_Wqkv + 2359296;               // 1024*1024*2
    const size_t o_W1   = o_Wo   + 2097152;               // 4096*1024*2
    const size_t o_W2   = o_W1   + 8388608;               // 1024*4096*2
    const size_t o_bqkv = o_W2   + 8388608;               // 1152*4
    const size_t O_XN   = 21238272;   // x_norm bf16 33554432 (later: attn)
    const size_t O_QKV  = 54792704;   // QKV bf16 37748736    (later: h_norm)
    const size_t O_S    = 92541440;   // S bf16 2097152
    const size_t O_DEN  = 94638592;   // den fp32 65536
    const size_t O_KSA  = 94704128;   // KsA fp32 65536
    const size_t O_KSP  = 94769664;   // KsP fp32 65536
    const size_t O_KVA  = 94835200;   // KV_A bf16 33.5MB (later: h-strip bf16 67MB)
    const size_t O_KVP  = 161944064;  // KV_P bf16 33554432

    uint16_t* Wqkv  = (uint16_t*)(ws + o_Wqkv);
    uint16_t* Wo    = (uint16_t*)(ws + o_Wo);
    uint16_t* W1    = (uint16_t*)(ws + o_W1);
    uint16_t* W2    = (uint16_t*)(ws + o_W2);
    float*    bqkv  = (float*)(ws + o_bqkv);
    uint16_t* xn    = (uint16_t*)(ws + O_XN);
    uint16_t* attn  = (uint16_t*)(ws + O_XN);   // alias: x_norm dead after QKV GEMM
    uint16_t* QKV   = (uint16_t*)(ws + O_QKV);
    uint16_t* hnorm = (uint16_t*)(ws + O_QKV);  // alias: QKV dead after phase C
    uint16_t* Sg    = (uint16_t*)(ws + O_S);
    float*    den   = (float*)(ws + O_DEN);
    float*    KsA   = (float*)(ws + O_KSA);
    float*    KsP   = (float*)(ws + O_KSP);
    uint16_t* KV_A  = (uint16_t*)(ws + O_KVA);
    uint16_t* hbuf  = (uint16_t*)(ws + O_KVA);  // alias: KV_A dead after prefix
    uint16_t* KV_P  = (uint16_t*)(ws + O_KVP);

    // 1. weight prep
    eel_prep<<<4096, 256, 0, stream>>>(qw, kw, vw, ow, f1w, f2w, qb, kb, vb,
                                       Wqkv, Wo, W1, W2, bqkv);
    // 2. LN1: x -> x_norm (bf16)
    eel_ln<<<16384, 256, 0, stream>>>(x, ln1w, ln1b, xn);
    // 3. QKV projection: [16384,1024] @ [1152,1024]^T -> QKV bf16, elu+1 on Q,K
    //    run as N=1280 (5 tiles), B-rows >= 1152 clamped, stores guarded.
    eel_gemm256<<<320, 512, 0, stream>>>(xn, 1024, Wqkv, 1024, 1152, 1024,
                                         bqkv, nullptr, QKV, nullptr, 1152, 0, 1152);
    // 4. phase A1: S, den_intra, Ks per chunk
    eel_attn_s<<<256, 256, 0, stream>>>(QKV, Sg, den, KsA);
    // 5. phase A2: per-chunk KV states (bf16)
    eel_attn_kv<<<2048, 256, 0, stream>>>(QKV, KV_A);
    // 6. phase B1: KV prefix (exclusive), bf16 in/out, fp32 accum
    eel_kv_prefix<<<1024, 256, 0, stream>>>(KV_A, KV_P);
    // 7. phase B2: Ks prefix
    eel_ks_prefix<<<4, 64, 0, stream>>>(KsA, KsP);
    // 8. phase C: attention output -> attn bf16 (aliases x_norm)
    eel_attn_out<<<2048, 256, 0, stream>>>(QKV, Sg, den, KsP, KV_P, attn);
    // 9. O-proj + residual: attn @ Wo^T + ob + x -> d_out (fp32)
    eel_gemm256<<<256, 512, 0, stream>>>(attn, 1024, Wo, 1024, 1024, 1024,
                                         ob, x, nullptr, out, 1024, 1, 1024);
    // 10. LN2: d_out -> h_norm bf16 (aliases QKV)
    eel_ln<<<16384, 256, 0, stream>>>(out, ln2w, ln2b, hnorm);
    // 11-14. FFN as two N-strips of 2048 over full M=16384:
    //   FFN1 strip: hnorm @ W1[strip]^T -> gelu -> h-strip bf16 [16384,2048]
    //   FFN2 strip: h-strip @ W2[:,strip]^T (+f2b on strip 0) + out -> out
    for (int strip = 0; strip < 2; strip++) {
        size_t noff = (size_t)strip * 2048;
        eel_gemm256<<<512, 512, 0, stream>>>(hnorm, 1024, W1 + noff * 1024, 1024, 2048,
                                             1024, f1b + noff, nullptr, hbuf, nullptr,
                                             2048, 2, 2048);
        eel_gemm256<<<256, 512, 0, stream>>>(hbuf, 2048, W2 + noff, 4096, 1024,
                                             2048, strip == 0 ? f2bs : nullptr, out,
                                             nullptr, out, 1024, 1, 1024);
    }
}

// Round 2
// 1007.582 us; speedup vs baseline: 1.1113x; 1.1113x over previous
//
#include <hip/hip_runtime.h>
#include <hip/hip_bf16.h>
#include <cstdint>
#include <cstddef>

// ---------------------------------------------------------------------------
// EfficientEquilibriumLayer: LN1 -> QKV(elu+1 on Q,K) -> chunked causal linear
// attention -> O-proj + residual -> LN2 -> GELU FFN + residual.
// B=4, N=4096, D=1024, F=64. All GEMMs bf16 MFMA (16x16x32), fp32 accum.
// R1: XOR-swizzled LDS (bank conflicts 2.5e7 -> 0), tanh-GELU epilogue.
// R2: FFN as N-strips over full M.
// R3: L2-locality block swizzle (bx == XCD mod 8 -> per-XCD A-slab reuse).
// R4: 256x256 deep-pipelined GEMM (4-buffer LDS ring, counted vmcnt(8),
//     setprio around MFMA). REGRESSED to 416 TF: (a) sched_barrier(0) after
//     every waitcnt order-pinned the scheduler (m141 signature, 0.58x), and
//     (b) bx-fastest XCD map made every XCD stream ALL of A (FETCH 2x).
// R5 (this): same pipeline, two fixes:
//     - no sched_barrier anywhere; waitcnt asm carries ::: "memory" clobber
//       (fences LDS/VMEM motion across waits, leaves VALU scheduling free --
//       matches the m201 template exactly).
//     - XCD map: tile = (blk&7)*qch + blk>>3, by fastest (bx = tile/nby).
//       Each XCD owns an 8-panel A-slab (~4MB, L2-resident, re-read nby x);
//       B strip shared via L3. Staging loads return at L2 latency, which the
//       3-tile-deep vmcnt(8) pipeline covers.
// ---------------------------------------------------------------------------

typedef __attribute__((ext_vector_type(8))) short short8;
typedef __attribute__((ext_vector_type(4))) short short4v;
typedef __attribute__((ext_vector_type(4))) float floatx4;
typedef __attribute__((ext_vector_type(4))) unsigned short ushort4v;

#define DEV static __device__ __forceinline__

DEV float b2f(unsigned short u) {
    union { unsigned int i; float f; } v; v.i = ((unsigned int)u) << 16; return v.f;
}
DEV unsigned short f2b(float f) {
    union { float f; unsigned int i; } v; v.f = f;
    unsigned int i = v.i;
    unsigned int r = (i + 0x7FFFu + ((i >> 16) & 1u)) >> 16;
    return (unsigned short)r;
}

DEV void gl_lds16(const void* g, void* l) {
    __builtin_amdgcn_global_load_lds((const __attribute__((address_space(1))) void*)g,
                                     (__attribute__((address_space(3))) void*)l, 16, 0, 0);
}

// ---------------------------------------------------------------------------
// Weight prep: fp32 -> bf16, concat q/k/v weights into Wqkv [1152,1024],
// concat biases into bqkv [1152].
// ---------------------------------------------------------------------------
__global__ void eel_prep(const float* __restrict__ qw, const float* __restrict__ kw,
                         const float* __restrict__ vw, const float* __restrict__ ow,
                         const float* __restrict__ f1w, const float* __restrict__ f2w,
                         const float* __restrict__ qb, const float* __restrict__ kb,
                         const float* __restrict__ vb,
                         uint16_t* __restrict__ Wqkv, uint16_t* __restrict__ Wo,
                         uint16_t* __restrict__ W1, uint16_t* __restrict__ W2,
                         float* __restrict__ bqkv)
{
    size_t i = (size_t)blockIdx.x * 256 + threadIdx.x;
    size_t stride = (size_t)gridDim.x * 256;
    for (size_t t = i; t < 1152u * 1024u; t += stride) {
        int r = (int)(t >> 10);
        float v = (r < 64) ? qw[t] : (r < 128) ? kw[t - 65536] : vw[t - 131072];
        Wqkv[t] = f2b(v);
    }
    for (size_t t = i; t < 1048576u; t += stride) Wo[t] = f2b(ow[t]);
    for (size_t t = i; t < 4194304u; t += stride) { W1[t] = f2b(f1w[t]); W2[t] = f2b(f2w[t]); }
    if (i < 1152) bqkv[i] = (i < 64) ? qb[i] : (i < 128) ? kb[i - 64] : vb[i - 128];
}

// ---------------------------------------------------------------------------
// LayerNorm: one block per row (D=1024), fp32 in -> bf16 out.
// ---------------------------------------------------------------------------
__global__ __launch_bounds__(256) void eel_ln(const float* __restrict__ x,
                                              const float* __restrict__ w,
                                              const float* __restrict__ b,
                                              uint16_t* __restrict__ out)
{
    int row = blockIdx.x, tid = threadIdx.x;
    float4 xv = ((const float4*)(x + (size_t)row * 1024))[tid];
    float s  = xv.x + xv.y + xv.z + xv.w;
    float s2 = xv.x*xv.x + xv.y*xv.y + xv.z*xv.z + xv.w*xv.w;
#pragma unroll
    for (int off = 32; off > 0; off >>= 1) {
        s  += __shfl_down(s, off);
        s2 += __shfl_down(s2, off);
    }
    __shared__ float ps[8];
    int wv = tid >> 6;
    if ((tid & 63) == 0) { ps[wv] = s; ps[4 + wv] = s2; }
    __syncthreads();
    float mu  = (ps[0] + ps[1] + ps[2] + ps[3]) * (1.0f / 1024.0f);
    float var = (ps[4] + ps[5] + ps[6] + ps[7]) * (1.0f / 1024.0f) - mu * mu;
    float rs = rsqrtf(var + 1e-5f);
    float4 wv4 = ((const float4*)w)[tid];
    float4 bv4 = ((const float4*)b)[tid];
    ushort4v o;
    o.x = f2b((xv.x - mu) * rs * wv4.x + bv4.x);
    o.y = f2b((xv.y - mu) * rs * wv4.y + bv4.y);
    o.z = f2b((xv.z - mu) * rs * wv4.z + bv4.z);
    o.w = f2b((xv.w - mu) * rs * wv4.w + bv4.w);
    *(ushort4v*)(out + (size_t)row * 1024 + tid * 4) = o;
}

// ---------------------------------------------------------------------------
// GEMM 256x256: C[M,N] = A[M,K] @ B[N,K]^T (+epilogue). bf16 in, fp32 accum.
// 512 threads = 8 waves (2M x 4N), per-wave 128x64 C. BK=32, ring of 4 LDS
// buffers (128 KiB total). Tile T+3 staged during tile T (A in phase 1, B in
// phase 2); boundary wait is s_waitcnt vmcnt(8) -- never 0 in the main loop.
// Swizzle seg' = seg ^ ((row>>1)&3) applied on the global source (LDS linear
// for global_load_lds); frag rows differ by multiples of 16 so the read-side
// XOR is thread-constant -> ds_read_b128 immediate offsets, 0 bank conflicts
// (verified R4 rocprof).
// Ring hazard: STAGE(T+3) -> buffer (T-1)&3; its last readers' ds_reads are
// consumed by MFMAs before T-1's trailing barrier, and the stage is issued
// after it. Landing of tile T confirmed by vmcnt(8) at end of T-1 (12 loads
// outstanding -> oldest 4 = tile T's A+B).
// XCD map: tile = (blk&7)*qch + blk>>3 (bijective, grid%8==0), decomposed
// by-fastest: bx = tile/nby, by = tile%nby (nby = grid/64). XCD k owns a
// contiguous 8-wide bx slab of A (L2-resident, re-read nby x); B via L3.
// mode 0: out bf16 = acc+bias, cols<128 get elu(x)+1         (QKV proj)
// mode 1: out fp32 = acc+[bias]+res                          (O-proj / FFN2)
// mode 2: out bf16 = gelu_tanh(acc+bias)                     (FFN1)
// bmax: B rows >= bmax read row 0 (finite garbage, never stored);
// nvalid: stores with col >= nvalid skipped.
// ---------------------------------------------------------------------------
__global__ __launch_bounds__(512, 2) void eel_gemm256(
    const uint16_t* __restrict__ A, int lda,
    const uint16_t* __restrict__ Bm, int ldb, int bmax,
    int K,
    const float* __restrict__ bias,
    const float* __restrict__ res,
    uint16_t* __restrict__ outb, float* __restrict__ outf,
    int ldc, int mode, int nvalid)
{
    __shared__ uint16_t sA[4][8192];   // 4 bufs x [256 rows][32 k] bf16
    __shared__ uint16_t sB[4][8192];
    int tid = threadIdx.x;
    int lane = tid & 63, w = tid >> 6;
    int quad = lane >> 4, l16 = lane & 15;

    // XCD-contiguous tile range, by fastest within each XCD's slab.
    int nblk = gridDim.x, qch = nblk >> 3;
    int nby  = nblk >> 6;                  // NBX = 64 (M = 16384) always
    int tile = (blockIdx.x & 7) * qch + (blockIdx.x >> 3);
    int bx = tile / nby, by = tile - bx * nby;
    int m0 = bx << 8, n0 = by << 8;

    int wr = (w >> 2) * 128;               // wave row base within tile
    int wc = (w & 3) * 64;                 // wave col base within tile
    int rA = wr + l16;
    int rB = wc + l16;

    floatx4 acc[8][4] = {};
    short8 a0, a1, a2, a3, b0, b1, b2, b3;

    // staging: thread t covers rows t>>2 and (t>>2)+128, k-segment t&3.
    // global source pre-swizzled: gs = seg ^ ((row>>1)&3)  (row+128 same).
    int srow = tid >> 2, sseg = tid & 3;
    int sgs  = sseg ^ ((srow >> 1) & 3);
    const uint16_t* aptr0 = A + (size_t)(m0 + srow) * lda + sgs * 8;
    const uint16_t* aptr1 = A + (size_t)(m0 + srow + 128) * lda + sgs * 8;
    int br0 = n0 + srow;       if (br0 >= bmax) br0 = 0;
    int br1 = n0 + srow + 128; if (br1 >= bmax) br1 = 0;
    const uint16_t* bptr0 = Bm + (size_t)br0 * ldb + sgs * 8;
    const uint16_t* bptr1 = Bm + (size_t)br1 * ldb + sgs * 8;

#define STAGE_A(Tn) do {                                                      \
    gl_lds16(aptr0 + (Tn) * 32, (char*)sA[(Tn) & 3] + tid * 16);              \
    gl_lds16(aptr1 + (Tn) * 32, (char*)sA[(Tn) & 3] + 8192 + tid * 16);       \
} while (0)
#define STAGE_B(Tn) do {                                                      \
    gl_lds16(bptr0 + (Tn) * 32, (char*)sB[(Tn) & 3] + tid * 16);              \
    gl_lds16(bptr1 + (Tn) * 32, (char*)sB[(Tn) & 3] + 8192 + tid * 16);       \
} while (0)
#define NOSTG do { } while (0)
#define FRG(buf, r) (*(const short8*)((const char*)(buf) + (size_t)(r) * 64 + \
                     ((quad ^ (((r) >> 1) & 3)) * 16)))
#define VMW8 asm volatile("s_waitcnt vmcnt(8)" ::: "memory")
#define VMW4 asm volatile("s_waitcnt vmcnt(4)" ::: "memory")
#define VMW0 asm volatile("s_waitcnt vmcnt(0)" ::: "memory")
#define LGKM0 asm volatile("s_waitcnt lgkmcnt(0)" ::: "memory")
#define MFMA16(bb) do {                                                                        \
    acc[(bb)+0][0]=__builtin_amdgcn_mfma_f32_16x16x32_bf16(a0,b0,acc[(bb)+0][0],0,0,0);        \
    acc[(bb)+0][1]=__builtin_amdgcn_mfma_f32_16x16x32_bf16(a0,b1,acc[(bb)+0][1],0,0,0);        \
    acc[(bb)+0][2]=__builtin_amdgcn_mfma_f32_16x16x32_bf16(a0,b2,acc[(bb)+0][2],0,0,0);        \
    acc[(bb)+0][3]=__builtin_amdgcn_mfma_f32_16x16x32_bf16(a0,b3,acc[(bb)+0][3],0,0,0);        \
    acc[(bb)+1][0]=__builtin_amdgcn_mfma_f32_16x16x32_bf16(a1,b0,acc[(bb)+1][0],0,0,0);        \
    acc[(bb)+1][1]=__builtin_amdgcn_mfma_f32_16x16x32_bf16(a1,b1,acc[(bb)+1][1],0,0,0);        \
    acc[(bb)+1][2]=__builtin_amdgcn_mfma_f32_16x16x32_bf16(a1,b2,acc[(bb)+1][2],0,0,0);        \
    acc[(bb)+1][3]=__builtin_amdgcn_mfma_f32_16x16x32_bf16(a1,b3,acc[(bb)+1][3],0,0,0);        \
    acc[(bb)+2][0]=__builtin_amdgcn_mfma_f32_16x16x32_bf16(a2,b0,acc[(bb)+2][0],0,0,0);        \
    acc[(bb)+2][1]=__builtin_amdgcn_mfma_f32_16x16x32_bf16(a2,b1,acc[(bb)+2][1],0,0,0);        \
    acc[(bb)+2][2]=__builtin_amdgcn_mfma_f32_16x16x32_bf16(a2,b2,acc[(bb)+2][2],0,0,0);        \
    acc[(bb)+2][3]=__builtin_amdgcn_mfma_f32_16x16x32_bf16(a2,b3,acc[(bb)+2][3],0,0,0);        \
    acc[(bb)+3][0]=__builtin_amdgcn_mfma_f32_16x16x32_bf16(a3,b0,acc[(bb)+3][0],0,0,0);        \
    acc[(bb)+3][1]=__builtin_amdgcn_mfma_f32_16x16x32_bf16(a3,b1,acc[(bb)+3][1],0,0,0);        \
    acc[(bb)+3][2]=__builtin_amdgcn_mfma_f32_16x16x32_bf16(a3,b2,acc[(bb)+3][2],0,0,0);        \
    acc[(bb)+3][3]=__builtin_amdgcn_mfma_f32_16x16x32_bf16(a3,b3,acc[(bb)+3][3],0,0,0);        \
} while (0)
#define PHASE1(bi, STG) do {                                                  \
    const uint16_t* Ab_ = sA[bi]; const uint16_t* Bb_ = sB[bi];               \
    a0 = FRG(Ab_, rA +  0); a1 = FRG(Ab_, rA + 16);                           \
    a2 = FRG(Ab_, rA + 32); a3 = FRG(Ab_, rA + 48);                           \
    b0 = FRG(Bb_, rB +  0); b1 = FRG(Bb_, rB + 16);                           \
    b2 = FRG(Bb_, rB + 32); b3 = FRG(Bb_, rB + 48);                           \
    STG;                                                                      \
    __builtin_amdgcn_s_barrier();                                             \
    LGKM0;                                                                    \
    __builtin_amdgcn_s_setprio(1);                                            \
    MFMA16(0);                                                                \
    __builtin_amdgcn_s_setprio(0);                                            \
    __builtin_amdgcn_s_barrier();                                             \
} while (0)
#define PHASE2(bi, STG, VM) do {                                              \
    const uint16_t* Ab_ = sA[bi];                                             \
    a0 = FRG(Ab_, rA + 64); a1 = FRG(Ab_, rA + 80);                           \
    a2 = FRG(Ab_, rA + 96); a3 = FRG(Ab_, rA + 112);                          \
    STG;                                                                      \
    __builtin_amdgcn_s_barrier();                                             \
    LGKM0;                                                                    \
    __builtin_amdgcn_s_setprio(1);                                            \
    MFMA16(4);                                                                \
    __builtin_amdgcn_s_setprio(0);                                            \
    VM;                                                                       \
    __builtin_amdgcn_s_barrier();                                             \
} while (0)

    // prologue: stage tiles 0,1,2 (12 loads/thread); confirm tile 0, keep 8
    // loads (tiles 1,2) in flight.
    STAGE_A(0); STAGE_B(0);
    STAGE_A(1); STAGE_B(1);
    STAGE_A(2); STAGE_B(2);
    VMW8;
    __builtin_amdgcn_s_barrier();

    int nT = K >> 5;
    int T = 0;
    for (; T < nT - 3; ++T) {
        int bi = T & 3;
        PHASE1(bi, STAGE_A(T + 3));
        PHASE2(bi, STAGE_B(T + 3), VMW8);
    }
    PHASE1(T & 3, NOSTG); PHASE2(T & 3, NOSTG, VMW4); ++T;
    PHASE1(T & 3, NOSTG); PHASE2(T & 3, NOSTG, VMW0); ++T;
    PHASE1(T & 3, NOSTG); PHASE2(T & 3, NOSTG, NOSTG);

    // epilogue
#pragma unroll
    for (int j = 0; j < 4; j++) {
        int col = n0 + wc + j * 16 + l16;
        if (col < nvalid) {
            float bv = bias ? bias[col] : 0.0f;
#pragma unroll
            for (int i = 0; i < 8; i++) {
#pragma unroll
                for (int r2 = 0; r2 < 4; r2++) {
                    int row = m0 + wr + i * 16 + quad * 4 + r2;
                    float v = acc[i][j][r2] + bv;
                    size_t off = (size_t)row * ldc + col;
                    if (mode == 0) {
                        if (col < 128) v = (v > 0.f) ? v + 1.f : __expf(v);
                        outb[off] = f2b(v);
                    } else if (mode == 1) {
                        outf[off] = v + res[off];
                    } else {
                        // gelu tanh-approx; tanh(u) = 1 - 2/(exp(2u)+1), inf-safe
                        float u = 0.7978845608028654f * v * (1.0f + 0.044715f * v * v);
                        float e = __expf(2.0f * u);
                        float t = 1.0f - 2.0f / (e + 1.0f);
                        v = 0.5f * v * (1.0f + t);
                        outb[off] = f2b(v);
                    }
                }
            }
        }
    }
#undef STAGE_A
#undef STAGE_B
#undef NOSTG
#undef FRG
#undef VMW8
#undef VMW4
#undef VMW0
#undef LGKM0
#undef MFMA16
#undef PHASE1
#undef PHASE2
}

// ---------------------------------------------------------------------------
// Attention phase A1: per chunk (64 tokens) compute S = causal(Q K^T) (bf16),
// den_intra[n] = rowsum(S), Ks_c[f] = colsum(K). One block per chunk.
// QKV layout: [16384][1152] bf16, Q at col 0, K at 64, V at 128.
// ---------------------------------------------------------------------------
__global__ __launch_bounds__(256) void eel_attn_s(
    const uint16_t* __restrict__ QKV,
    uint16_t* __restrict__ Sg,      // [16384][64]
    float* __restrict__ den,        // [16384]
    float* __restrict__ KsA)        // [256][64]
{
    int chunk = blockIdx.x, tid = threadIdx.x;
    int tok0 = chunk * 64;
    __shared__ uint16_t Q[64 * 64];
    __shared__ uint16_t Kc[64 * 64];
    __shared__ float denp[64][4];
    {
        int nloc = tid >> 2, seg = tid & 3;
        const uint16_t* src = QKV + (size_t)(tok0 + nloc) * 1152 + seg * 16;
        *(short8*)(Q + nloc * 64 + seg * 16)     = *(const short8*)(src);
        *(short8*)(Q + nloc * 64 + seg * 16 + 8) = *(const short8*)(src + 8);
        src += 64;
        *(short8*)(Kc + nloc * 64 + seg * 16)     = *(const short8*)(src);
        *(short8*)(Kc + nloc * 64 + seg * 16 + 8) = *(const short8*)(src + 8);
    }
    __syncthreads();
    if (tid < 64) {
        float s = 0.f;
        for (int m = 0; m < 64; m++) s += b2f(Kc[m * 64 + tid]);
        KsA[chunk * 64 + tid] = s;
    }
    int n = tid >> 2, mg = tid & 3;
    float dsum = 0.f;
    for (int mi = 0; mi < 16; mi++) {
        int m = mg * 16 + mi;
        size_t soff = (size_t)(tok0 + n) * 64 + m;
        if (m <= n) {
            float s = 0.f;
#pragma unroll
            for (int f = 0; f < 64; f += 8) {
                short8 q8 = *(const short8*)(Q + n * 64 + f);
                short8 k8 = *(const short8*)(Kc + m * 64 + f);
#pragma unroll
                for (int j = 0; j < 8; j++)
                    s += b2f((unsigned short)q8[j]) * b2f((unsigned short)k8[j]);
            }
            dsum += s;
            Sg[soff] = f2b(s);
        } else {
            Sg[soff] = 0;
        }
    }
    denp[n][mg] = dsum;
    __syncthreads();
    if (tid < 64)
        den[tok0 + tid] = denp[tid][0] + denp[tid][1] + denp[tid][2] + denp[tid][3];
}

// ---------------------------------------------------------------------------
// Attention phase A2: per (chunk, d-panel of 128) compute KV_c[f, d] = K^T V.
// Output bf16 [256 chunks][64 f][1024 d].
// ---------------------------------------------------------------------------
__global__ __launch_bounds__(256) void eel_attn_kv(
    const uint16_t* __restrict__ QKV,
    uint16_t* __restrict__ KV_A)
{
    int bi = blockIdx.x;
    int chunk = bi >> 3, p = bi & 7;
    int tid = threadIdx.x;
    int tok0 = chunk * 64;
    __shared__ uint16_t Kc[64 * 64];
    __shared__ uint16_t Vp[64 * 128];
    {
        int r = tid >> 2, sg = tid & 3;
        const uint16_t* src = QKV + (size_t)(tok0 + r) * 1152 + 64 + sg * 16;
        *(short8*)(Kc + r * 64 + sg * 16)     = *(const short8*)(src);
        *(short8*)(Kc + r * 64 + sg * 16 + 8) = *(const short8*)(src + 8);
    }
#pragma unroll
    for (int it = 0; it < 2; it++) {
        int s = it * 256 + tid;
        int r = s >> 3, sub = s & 7;
        const uint16_t* src = QKV + (size_t)(tok0 + r) * 1152 + 128 + p * 128 + sub * 16;
        *(short8*)(Vp + r * 128 + sub * 16)     = *(const short8*)(src);
        *(short8*)(Vp + r * 128 + sub * 16 + 8) = *(const short8*)(src + 8);
    }
    __syncthreads();
    int f0 = (tid >> 5) * 8, d0 = (tid & 31) * 4;
    float acc[8][4] = {};
#pragma unroll 2
    for (int m = 0; m < 64; m++) {
        short8 k8 = *(const short8*)(Kc + m * 64 + f0);
        short4v v4 = *(const short4v*)(Vp + m * 128 + d0);
        float v0 = b2f((unsigned short)v4[0]), v1 = b2f((unsigned short)v4[1]);
        float v2 = b2f((unsigned short)v4[2]), v3 = b2f((unsigned short)v4[3]);
#pragma unroll
        for (int i = 0; i < 8; i++) {
            float kk = b2f((unsigned short)k8[i]);
            acc[i][0] += kk * v0; acc[i][1] += kk * v1;
            acc[i][2] += kk * v2; acc[i][3] += kk * v3;
        }
    }
#pragma unroll
    for (int i = 0; i < 8; i++) {
        ushort4v st;
        st.x = f2b(acc[i][0]); st.y = f2b(acc[i][1]);
        st.z = f2b(acc[i][2]); st.w = f2b(acc[i][3]);
        *(ushort4v*)(KV_A + ((size_t)chunk * 64 + f0 + i) * 1024 + p * 128 + d0) = st;
    }
}

// ---------------------------------------------------------------------------
// Phase B1: exclusive prefix over 64 chunks per batch of KV states (bf16 in,
// fp32 accum, bf16 out). Grid: 1024 blocks (b*256 + f*4 + dseg), 256 threads.
// ---------------------------------------------------------------------------
__global__ __launch_bounds__(256) void eel_kv_prefix(
    const uint16_t* __restrict__ KV_A, uint16_t* __restrict__ KV_P)
{
    int bi = blockIdx.x;
    int b = bi >> 8, rem = bi & 255;
    int f = rem >> 2;
    int d = (rem & 3) * 256 + threadIdx.x;
    float acc = 0.f;
    for (int cc = 0; cc < 64; cc++) {
        size_t idx = (((size_t)(b * 64 + cc)) * 64 + f) * 1024 + d;
        KV_P[idx] = f2b(acc);
        acc += b2f(KV_A[idx]);
    }
}

// Phase B2: exclusive prefix of Ks over chunks. Grid 4 x 64 threads.
__global__ void eel_ks_prefix(const float* __restrict__ KsA, float* __restrict__ KsP)
{
    int b = blockIdx.x, f = threadIdx.x;
    float acc = 0.f;
    for (int cc = 0; cc < 64; cc++) {
        int idx = (b * 64 + cc) * 64 + f;
        KsP[idx] = acc;
        acc += KsA[idx];
    }
}

// ---------------------------------------------------------------------------
// Phase C: per (chunk, d-panel) attn[n,d] = (Q·KV_prev + S·V) / den_full.
// ---------------------------------------------------------------------------
__global__ __launch_bounds__(256) void eel_attn_out(
    const uint16_t* __restrict__ QKV,
    const uint16_t* __restrict__ Sg,
    const float* __restrict__ den,
    const float* __restrict__ KsP,
    const uint16_t* __restrict__ KV_P,
    uint16_t* __restrict__ attn)    // [16384][1024] bf16
{
    int bi = blockIdx.x;
    int chunk = bi >> 3, p = bi & 7;
    int tid = threadIdx.x;
    int tok0 = chunk * 64;
    __shared__ uint16_t Qt[64 * 64];    // [f][n]
    __shared__ uint16_t St[64 * 64];    // [m][n]
    __shared__ uint16_t Vp[64 * 128];   // [m][d]
    __shared__ uint16_t KVp[64 * 128];  // [f][d]
    __shared__ float dfull[64];
    {
        int n = tid >> 2, fs = (tid & 3) * 16;
        const uint16_t* qsrc = QKV + (size_t)(tok0 + n) * 1152 + fs;
        short8 a0 = *(const short8*)(qsrc);
        short8 a1 = *(const short8*)(qsrc + 8);
        const uint16_t* ssrc = Sg + (size_t)(tok0 + n) * 64 + fs;
        short8 s0 = *(const short8*)(ssrc);
        short8 s1 = *(const short8*)(ssrc + 8);
#pragma unroll
        for (int j = 0; j < 8; j++) {
            Qt[(fs + j) * 64 + n]     = (unsigned short)a0[j];
            Qt[(fs + 8 + j) * 64 + n] = (unsigned short)a1[j];
            St[(fs + j) * 64 + n]     = (unsigned short)s0[j];
            St[(fs + 8 + j) * 64 + n] = (unsigned short)s1[j];
        }
    }
#pragma unroll
    for (int it = 0; it < 2; it++) {
        int s = it * 256 + tid;
        int r = s >> 3, sub = s & 7;
        const uint16_t* vsrc = QKV + (size_t)(tok0 + r) * 1152 + 128 + p * 128 + sub * 16;
        *(short8*)(Vp + r * 128 + sub * 16)     = *(const short8*)(vsrc);
        *(short8*)(Vp + r * 128 + sub * 16 + 8) = *(const short8*)(vsrc + 8);
        const uint16_t* kvsrc = KV_P + ((size_t)(chunk * 64 + r)) * 1024 + p * 128 + sub * 16;
        *(short8*)(KVp + r * 128 + sub * 16)     = *(const short8*)(kvsrc);
        *(short8*)(KVp + r * 128 + sub * 16 + 8) = *(const short8*)(kvsrc + 8);
    }
    __syncthreads();
    if (tid < 64) {
        float s = 0.f;
        for (int f = 0; f < 64; f++)
            s += b2f(Qt[f * 64 + tid]) * KsP[chunk * 64 + f];
        dfull[tid] = s + den[tok0 + tid] + 1e-6f;
    }
    __syncthreads();
    int n0 = (tid >> 5) * 8, d0 = (tid & 31) * 4;
    float acc[8][4] = {};
#pragma unroll 2
    for (int f = 0; f < 64; f++) {
        short8 q8 = *(const short8*)(Qt + f * 64 + n0);
        short4v kv4 = *(const short4v*)(KVp + f * 128 + d0);
        float v0 = b2f((unsigned short)kv4[0]), v1 = b2f((unsigned short)kv4[1]);
        float v2 = b2f((unsigned short)kv4[2]), v3 = b2f((unsigned short)kv4[3]);
#pragma unroll
        for (int i = 0; i < 8; i++) {
            float q = b2f((unsigned short)q8[i]);
            acc[i][0] += q * v0; acc[i][1] += q * v1;
            acc[i][2] += q * v2; acc[i][3] += q * v3;
        }
    }
#pragma unroll 2
    for (int m = 0; m < 64; m++) {
        short8 s8 = *(const short8*)(St + m * 64 + n0);
        short4v v4 = *(const short4v*)(Vp + m * 128 + d0);
        float v0 = b2f((unsigned short)v4[0]), v1 = b2f((unsigned short)v4[1]);
        float v2 = b2f((unsigned short)v4[2]), v3 = b2f((unsigned short)v4[3]);
#pragma unroll
        for (int i = 0; i < 8; i++) {
            float q = b2f((unsigned short)s8[i]);
            acc[i][0] += q * v0; acc[i][1] += q * v1;
            acc[i][2] += q * v2; acc[i][3] += q * v3;
        }
    }
#pragma unroll
    for (int i = 0; i < 8; i++) {
        int n = n0 + i;
        float rinv = 1.0f / dfull[n];
        ushort4v st;
        st.x = f2b(acc[i][0] * rinv);
        st.y = f2b(acc[i][1] * rinv);
        st.z = f2b(acc[i][2] * rinv);
        st.w = f2b(acc[i][3] * rinv);
        *(ushort4v*)(attn + (size_t)(tok0 + n) * 1024 + p * 128 + d0) = st;
    }
}

// ---------------------------------------------------------------------------
// Host launcher
// ---------------------------------------------------------------------------
extern "C" void kernel_launch(void* const* d_in, const int* in_sizes, int n_in,
                              void* d_out, int out_size, void* d_ws, size_t ws_size,
                              hipStream_t stream)
{
    (void)in_sizes; (void)n_in; (void)out_size; (void)ws_size;
    const float* x     = (const float*)d_in[0];
    const float* ln1w  = (const float*)d_in[1];
    const float* ln1b  = (const float*)d_in[2];
    const float* qw    = (const float*)d_in[3];
    const float* qb    = (const float*)d_in[4];
    const float* kw    = (const float*)d_in[5];
    const float* kb    = (const float*)d_in[6];
    const float* vw    = (const float*)d_in[7];
    const float* vb    = (const float*)d_in[8];
    const float* ow    = (const float*)d_in[9];
    const float* ob    = (const float*)d_in[10];
    const float* ln2w  = (const float*)d_in[11];
    const float* ln2b  = (const float*)d_in[12];
    const float* f1w   = (const float*)d_in[13];
    const float* f1b   = (const float*)d_in[14];
    const float* f2w   = (const float*)d_in[15];
    const float* f2bs  = (const float*)d_in[16];
    float* out = (float*)d_out;
    char* ws = (char*)d_ws;

    // workspace layout (bytes)
    const size_t o_Wqkv = 0;                              // 1152*1024*2
    const size_t o_Wo   = o_Wqkv + 2359296;               // 1024*1024*2
    const size_t o_W1   = o_Wo   + 2097152;               // 4096*1024*2
    const size_t o_W2   = o_W1   + 8388608;               // 1024*4096*2
    const size_t o_bqkv = o_W2   + 8388608;               // 1152*4
    const size_t O_XN   = 21238272;   // x_norm bf16 33554432 (later: attn)
    const size_t O_QKV  = 54792704;   // QKV bf16 37748736    (later: h_norm)
    const size_t O_S    = 92541440;   // S bf16 2097152
    const size_t O_DEN  = 94638592;   // den fp32 65536
    const size_t O_KSA  = 94704128;   // KsA fp32 65536
    const size_t O_KSP  = 94769664;   // KsP fp32 65536
    const size_t O_KVA  = 94835200;   // KV_A bf16 33.5MB (later: h-strip bf16 67MB)
    const size_t O_KVP  = 161944064;  // KV_P bf16 33554432

    uint16_t* Wqkv  = (uint16_t*)(ws + o_Wqkv);
    uint16_t* Wo    = (uint16_t*)(ws + o_Wo);
    uint16_t* W1    = (uint16_t*)(ws + o_W1);
    uint16_t* W2    = (uint16_t*)(ws + o_W2);
    float*    bqkv  = (float*)(ws + o_bqkv);
    uint16_t* xn    = (uint16_t*)(ws + O_XN);
    uint16_t* attn  = (uint16_t*)(ws + O_XN);   // alias: x_norm dead after QKV GEMM
    uint16_t* QKV   = (uint16_t*)(ws + O_QKV);
    uint16_t* hnorm = (uint16_t*)(ws + O_QKV);  // alias: QKV dead after phase C
    uint16_t* Sg    = (uint16_t*)(ws + O_S);
    float*    den   = (float*)(ws + O_DEN);
    float*    KsA   = (float*)(ws + O_KSA);
    float*    KsP   = (float*)(ws + O_KSP);
    uint16_t* KV_A  = (uint16_t*)(ws + O_KVA);
    uint16_t* hbuf  = (uint16_t*)(ws + O_KVA);  // alias: KV_A dead after prefix
    uint16_t* KV_P  = (uint16_t*)(ws + O_KVP);

    // 1. weight prep
    eel_prep<<<4096, 256, 0, stream>>>(qw, kw, vw, ow, f1w, f2w, qb, kb, vb,
                                       Wqkv, Wo, W1, W2, bqkv);
    // 2. LN1: x -> x_norm (bf16)
    eel_ln<<<16384, 256, 0, stream>>>(x, ln1w, ln1b, xn);
    // 3. QKV projection: [16384,1024] @ [1152,1024]^T -> QKV bf16, elu+1 on Q,K
    //    run as N=1280 (5 tiles), B-rows >= 1152 clamped, stores guarded.
    eel_gemm256<<<320, 512, 0, stream>>>(xn, 1024, Wqkv, 1024, 1152, 1024,
                                         bqkv, nullptr, QKV, nullptr, 1152, 0, 1152);
    // 4. phase A1: S, den_intra, Ks per chunk
    eel_attn_s<<<256, 256, 0, stream>>>(QKV, Sg, den, KsA);
    // 5. phase A2: per-chunk KV states (bf16)
    eel_attn_kv<<<2048, 256, 0, stream>>>(QKV, KV_A);
    // 6. phase B1: KV prefix (exclusive), bf16 in/out, fp32 accum
    eel_kv_prefix<<<1024, 256, 0, stream>>>(KV_A, KV_P);
    // 7. phase B2: Ks prefix
    eel_ks_prefix<<<4, 64, 0, stream>>>(KsA, KsP);
    // 8. phase C: attention output -> attn bf16 (aliases x_norm)
    eel_attn_out<<<2048, 256, 0, stream>>>(QKV, Sg, den, KsP, KV_P, attn);
    // 9. O-proj + residual: attn @ Wo^T + ob + x -> d_out (fp32)
    eel_gemm256<<<256, 512, 0, stream>>>(attn, 1024, Wo, 1024, 1024, 1024,
                                         ob, x, nullptr, out, 1024, 1, 1024);
    // 10. LN2: d_out -> h_norm bf16 (aliases QKV)
    eel_ln<<<16384, 256, 0, stream>>>(out, ln2w, ln2b, hnorm);
    // 11-14. FFN as two N-strips of 2048 over full M=16384:
    //   FFN1 strip: hnorm @ W1[strip]^T -> gelu -> h-strip bf16 [16384,2048]
    //   FFN2 strip: h-strip @ W2[:,strip]^T (+f2b on strip 0) + out -> out
    for (int strip = 0; strip < 2; strip++) {
        size_t noff = (size_t)strip * 2048;
        eel_gemm256<<<512, 512, 0, stream>>>(hnorm, 1024, W1 + noff * 1024, 1024, 2048,
                                             1024, f1b + noff, nullptr, hbuf, nullptr,
                                             2048, 2, 2048);
        eel_gemm256<<<256, 512, 0, stream>>>(hbuf, 2048, W2 + noff, 4096, 1024,
                                             2048, strip == 0 ? f2bs : nullptr, out,
                                             nullptr, out, 1024, 1, 1024);
    }
}

// Round 3
// 762.519 us; speedup vs baseline: 1.4685x; 1.3214x over previous
//
#include <hip/hip_runtime.h>
#include <hip/hip_bf16.h>
#include <cstdint>
#include <cstddef>

// ---------------------------------------------------------------------------
// EfficientEquilibriumLayer: LN1 -> QKV(elu+1 on Q,K) -> chunked causal linear
// attention -> O-proj + residual -> LN2 -> GELU FFN + residual.
// B=4, N=4096, D=1024, F=64. All GEMMs bf16 MFMA (16x16x32), fp32 accum.
// R1: XOR-swizzled LDS (bank conflicts 2.5e7 -> 0), tanh-GELU epilogue.
// R2: FFN as N-strips over full M.
// R3: L2-locality block swizzle in eel_gemm (verified 816-857us end-to-end).
// R4/R5: 256x256 deep-pipelined GEMM attempts -- REGRESSED (phase time ~2900cy
//     independent of memory locality; structure stall not diagnosable from
//     counters). Reverted: eel_gemm below is the R3-verified kernel verbatim.
// R6 (this): MFMA-ize the two matmul-shaped attention kernels (were scalar
//     VALU FMA loops, ~135us combined):
//     - eel_attn_kv: KV_c[f][d] = K^T V via mfma_16x16x32; K^T [f][m] and
//       V^T [d][m] built by scalar-transpose staging into pad-72 LDS rows
//       (144B stride = uniform bank spread). Output layout unchanged.
//     - eel_attn_out: O = Q.KV_P + S.V via MFMA; Q,S are native A-operands
//       (vector-staged), KV_P^T/V^T transpose-staged. dfull path unchanged.
//     Fragment conventions identical to the proven eel_gemm in this file.
// ---------------------------------------------------------------------------

typedef __attribute__((ext_vector_type(8))) short short8;
typedef __attribute__((ext_vector_type(4))) short short4v;
typedef __attribute__((ext_vector_type(4))) float floatx4;
typedef __attribute__((ext_vector_type(4))) unsigned short ushort4v;

#define DEV static __device__ __forceinline__

DEV float b2f(unsigned short u) {
    union { unsigned int i; float f; } v; v.i = ((unsigned int)u) << 16; return v.f;
}
DEV unsigned short f2b(float f) {
    union { float f; unsigned int i; } v; v.f = f;
    unsigned int i = v.i;
    unsigned int r = (i + 0x7FFFu + ((i >> 16) & 1u)) >> 16;
    return (unsigned short)r;
}

DEV void gl_lds16(const void* g, void* l) {
    __builtin_amdgcn_global_load_lds((const __attribute__((address_space(1))) void*)g,
                                     (__attribute__((address_space(3))) void*)l, 16, 0, 0);
}

// ---------------------------------------------------------------------------
// Weight prep: fp32 -> bf16, concat q/k/v weights into Wqkv [1152,1024],
// concat biases into bqkv [1152].
// ---------------------------------------------------------------------------
__global__ void eel_prep(const float* __restrict__ qw, const float* __restrict__ kw,
                         const float* __restrict__ vw, const float* __restrict__ ow,
                         const float* __restrict__ f1w, const float* __restrict__ f2w,
                         const float* __restrict__ qb, const float* __restrict__ kb,
                         const float* __restrict__ vb,
                         uint16_t* __restrict__ Wqkv, uint16_t* __restrict__ Wo,
                         uint16_t* __restrict__ W1, uint16_t* __restrict__ W2,
                         float* __restrict__ bqkv)
{
    size_t i = (size_t)blockIdx.x * 256 + threadIdx.x;
    size_t stride = (size_t)gridDim.x * 256;
    for (size_t t = i; t < 1152u * 1024u; t += stride) {
        int r = (int)(t >> 10);
        float v = (r < 64) ? qw[t] : (r < 128) ? kw[t - 65536] : vw[t - 131072];
        Wqkv[t] = f2b(v);
    }
    for (size_t t = i; t < 1048576u; t += stride) Wo[t] = f2b(ow[t]);
    for (size_t t = i; t < 4194304u; t += stride) { W1[t] = f2b(f1w[t]); W2[t] = f2b(f2w[t]); }
    if (i < 1152) bqkv[i] = (i < 64) ? qb[i] : (i < 128) ? kb[i - 64] : vb[i - 128];
}

// ---------------------------------------------------------------------------
// LayerNorm: one block per row (D=1024), fp32 in -> bf16 out.
// ---------------------------------------------------------------------------
__global__ __launch_bounds__(256) void eel_ln(const float* __restrict__ x,
                                              const float* __restrict__ w,
                                              const float* __restrict__ b,
                                              uint16_t* __restrict__ out)
{
    int row = blockIdx.x, tid = threadIdx.x;
    float4 xv = ((const float4*)(x + (size_t)row * 1024))[tid];
    float s  = xv.x + xv.y + xv.z + xv.w;
    float s2 = xv.x*xv.x + xv.y*xv.y + xv.z*xv.z + xv.w*xv.w;
#pragma unroll
    for (int off = 32; off > 0; off >>= 1) {
        s  += __shfl_down(s, off);
        s2 += __shfl_down(s2, off);
    }
    __shared__ float ps[8];
    int wv = tid >> 6;
    if ((tid & 63) == 0) { ps[wv] = s; ps[4 + wv] = s2; }
    __syncthreads();
    float mu  = (ps[0] + ps[1] + ps[2] + ps[3]) * (1.0f / 1024.0f);
    float var = (ps[4] + ps[5] + ps[6] + ps[7]) * (1.0f / 1024.0f) - mu * mu;
    float rs = rsqrtf(var + 1e-5f);
    float4 wv4 = ((const float4*)w)[tid];
    float4 bv4 = ((const float4*)b)[tid];
    ushort4v o;
    o.x = f2b((xv.x - mu) * rs * wv4.x + bv4.x);
    o.y = f2b((xv.y - mu) * rs * wv4.y + bv4.y);
    o.z = f2b((xv.z - mu) * rs * wv4.z + bv4.z);
    o.w = f2b((xv.w - mu) * rs * wv4.w + bv4.w);
    *(ushort4v*)(out + (size_t)row * 1024 + tid * 4) = o;
}

// ---------------------------------------------------------------------------
// GEMM (R3-verified): C[M,N] = A[M,K] @ B[N,K]^T (+epilogue). bf16, fp32 acc.
// 128x128 tile, BK=64, 4 waves, 16x16x32 MFMA, global_load_lds staging,
// XOR-swizzled LDS k-segments (conflict-free ds_read_b128).
// Block swizzle: y fastest within groups of 8 x-panels (weight tiles L2-hot).
// Requires gridDim.x % 8 == 0 (all call sites use 64/128).
// mode 0: out bf16 = acc+bias, cols<128 get elu(x)+1         (QKV proj)
// mode 1: out fp32 = acc+[bias]+res                          (O-proj / FFN2)
// mode 2: out bf16 = gelu_tanh(acc+bias)                     (FFN1)
// ---------------------------------------------------------------------------
#define BM 128
#define BN 128
#define BKK 64

__global__ __launch_bounds__(256, 2) void eel_gemm(
    const uint16_t* __restrict__ A, int lda,
    const uint16_t* __restrict__ Bm, int ldb,
    int K,
    const float* __restrict__ bias,
    const float* __restrict__ res,
    uint16_t* __restrict__ outb,
    float* __restrict__ outf,
    int ldc, int mode)
{
    __shared__ uint16_t As[BM * BKK];
    __shared__ uint16_t Bs[BN * BKK];
    int tid = threadIdx.x;
    int lane = tid & 63, w = tid >> 6;
    // L2-locality swizzle: linear id -> (bx, by) with by fastest in 8-wide
    // x-groups, so co-resident blocks share the weight (B) strip.
    int lin  = blockIdx.y * gridDim.x + blockIdx.x;
    int span = 8 * gridDim.y;
    int g = lin / span, r = lin % span;
    int bx = g * 8 + (r & 7);
    int by = r >> 3;
    int m0 = bx * BM, n0 = by * BN;
    int wr = (w >> 1) * 64, wc = (w & 1) * 64;
    int quad = lane >> 4, l16 = lane & 15;
    floatx4 acc[4][4] = {};

    int nkb = K / BKK;
    for (int kb = 0; kb < nkb; ++kb) {
        int k0 = kb * BKK;
#pragma unroll
        for (int it = 0; it < 4; ++it) {
            int seg = it * 256 + tid;
            int row = seg >> 3, sub = seg & 7;
            int gs = sub ^ (row & 7);   // source k-segment for swizzled slot
            gl_lds16(A + (size_t)(m0 + row) * lda + k0 + gs * 8, (char*)As + seg * 16);
            gl_lds16(Bm + (size_t)(n0 + row) * ldb + k0 + gs * 8, (char*)Bs + seg * 16);
        }
        __syncthreads();
#pragma unroll
        for (int ks = 0; ks < 2; ++ks) {
            short8 a[4], b[4];
#pragma unroll
            for (int i = 0; i < 4; i++) {
                int mrow = wr + i * 16 + l16;
                int sa = (ks * 4 + quad) ^ (mrow & 7);
                a[i] = *(const short8*)((const char*)As + mrow * (BKK * 2) + sa * 16);
                int nrow = wc + i * 16 + l16;
                int sb = (ks * 4 + quad) ^ (nrow & 7);
                b[i] = *(const short8*)((const char*)Bs + nrow * (BKK * 2) + sb * 16);
            }
#pragma unroll
            for (int i = 0; i < 4; i++)
#pragma unroll
                for (int j = 0; j < 4; j++)
                    acc[i][j] = __builtin_amdgcn_mfma_f32_16x16x32_bf16(a[i], b[j], acc[i][j], 0, 0, 0);
        }
        __syncthreads();
    }

#pragma unroll
    for (int j = 0; j < 4; j++) {
        int col = n0 + wc + j * 16 + l16;
        float bv = bias ? bias[col] : 0.0f;
#pragma unroll
        for (int i = 0; i < 4; i++) {
#pragma unroll
            for (int r2 = 0; r2 < 4; r2++) {
                int row = m0 + wr + i * 16 + quad * 4 + r2;
                float v = acc[i][j][r2] + bv;
                size_t off = (size_t)row * ldc + col;
                if (mode == 0) {
                    if (col < 128) v = (v > 0.f) ? v + 1.f : __expf(v);
                    outb[off] = f2b(v);
                } else if (mode == 1) {
                    outf[off] = v + res[off];
                } else {
                    // gelu tanh-approx; tanh(u) = 1 - 2/(exp(2u)+1), inf-safe
                    float u = 0.7978845608028654f * v * (1.0f + 0.044715f * v * v);
                    float e = __expf(2.0f * u);
                    float t = 1.0f - 2.0f / (e + 1.0f);
                    v = 0.5f * v * (1.0f + t);
                    outb[off] = f2b(v);
                }
            }
        }
    }
}

// ---------------------------------------------------------------------------
// Attention phase A1: per chunk (64 tokens) compute S = causal(Q K^T) (bf16),
// den_intra[n] = rowsum(S), Ks_c[f] = colsum(K). One block per chunk.
// QKV layout: [16384][1152] bf16, Q at col 0, K at 64, V at 128.
// ---------------------------------------------------------------------------
__global__ __launch_bounds__(256) void eel_attn_s(
    const uint16_t* __restrict__ QKV,
    uint16_t* __restrict__ Sg,      // [16384][64]
    float* __restrict__ den,        // [16384]
    float* __restrict__ KsA)        // [256][64]
{
    int chunk = blockIdx.x, tid = threadIdx.x;
    int tok0 = chunk * 64;
    __shared__ uint16_t Q[64 * 64];
    __shared__ uint16_t Kc[64 * 64];
    __shared__ float denp[64][4];
    {
        int nloc = tid >> 2, seg = tid & 3;
        const uint16_t* src = QKV + (size_t)(tok0 + nloc) * 1152 + seg * 16;
        *(short8*)(Q + nloc * 64 + seg * 16)     = *(const short8*)(src);
        *(short8*)(Q + nloc * 64 + seg * 16 + 8) = *(const short8*)(src + 8);
        src += 64;
        *(short8*)(Kc + nloc * 64 + seg * 16)     = *(const short8*)(src);
        *(short8*)(Kc + nloc * 64 + seg * 16 + 8) = *(const short8*)(src + 8);
    }
    __syncthreads();
    if (tid < 64) {
        float s = 0.f;
        for (int m = 0; m < 64; m++) s += b2f(Kc[m * 64 + tid]);
        KsA[chunk * 64 + tid] = s;
    }
    int n = tid >> 2, mg = tid & 3;
    float dsum = 0.f;
    for (int mi = 0; mi < 16; mi++) {
        int m = mg * 16 + mi;
        size_t soff = (size_t)(tok0 + n) * 64 + m;
        if (m <= n) {
            float s = 0.f;
#pragma unroll
            for (int f = 0; f < 64; f += 8) {
                short8 q8 = *(const short8*)(Q + n * 64 + f);
                short8 k8 = *(const short8*)(Kc + m * 64 + f);
#pragma unroll
                for (int j = 0; j < 8; j++)
                    s += b2f((unsigned short)q8[j]) * b2f((unsigned short)k8[j]);
            }
            dsum += s;
            Sg[soff] = f2b(s);
        } else {
            Sg[soff] = 0;
        }
    }
    denp[n][mg] = dsum;
    __syncthreads();
    if (tid < 64)
        den[tok0 + tid] = denp[tid][0] + denp[tid][1] + denp[tid][2] + denp[tid][3];
}

// ---------------------------------------------------------------------------
// Attention phase A2 (R6: MFMA): per (chunk, d-panel of 128) compute
// KV_c[f,d] = sum_m K[m,f] V[m,d] as D[f][d] = Kt[f][m] x Vt[d][m] with
// mfma_16x16x32. Kt/Vt built by scalar-transpose staging, rows padded to 72
// elems (144B stride -> uniform bank spread on frag reads and writes).
// Output layout unchanged: KV_A [256 chunks][64 f][1024 d] bf16.
// ---------------------------------------------------------------------------
__global__ __launch_bounds__(256) void eel_attn_kv(
    const uint16_t* __restrict__ QKV,
    uint16_t* __restrict__ KV_A)
{
    int bi = blockIdx.x;
    int chunk = bi >> 3, p = bi & 7;
    int tid = threadIdx.x;
    int tok0 = chunk * 64;
    __shared__ uint16_t Kt[64 * 72];    // [f][m], pad 72
    __shared__ uint16_t Vt[128 * 72];   // [d][m], pad 72
    {
        int m = tid >> 2, fs = (tid & 3) * 16;
        const uint16_t* src = QKV + (size_t)(tok0 + m) * 1152 + 64 + fs;
        short8 k0 = *(const short8*)(src);
        short8 k1 = *(const short8*)(src + 8);
#pragma unroll
        for (int j = 0; j < 8; j++) {
            Kt[(fs + j) * 72 + m]     = (unsigned short)k0[j];
            Kt[(fs + 8 + j) * 72 + m] = (unsigned short)k1[j];
        }
    }
#pragma unroll
    for (int it = 0; it < 2; it++) {
        int s = it * 256 + tid;
        int m = s >> 3, d0 = (s & 7) * 16;
        const uint16_t* src = QKV + (size_t)(tok0 + m) * 1152 + 128 + p * 128 + d0;
        short8 v0 = *(const short8*)(src);
        short8 v1 = *(const short8*)(src + 8);
#pragma unroll
        for (int j = 0; j < 8; j++) {
            Vt[(d0 + j) * 72 + m]     = (unsigned short)v0[j];
            Vt[(d0 + 8 + j) * 72 + m] = (unsigned short)v1[j];
        }
    }
    __syncthreads();
    int lane = tid & 63, w = tid >> 6;
    int quad = lane >> 4, l16 = lane & 15;
    floatx4 acc[4][2] = {};
#pragma unroll
    for (int ks = 0; ks < 2; ks++) {
        int ko = ks * 32 + quad * 8;
        short8 a[4], b[2];
#pragma unroll
        for (int i = 0; i < 4; i++)
            a[i] = *(const short8*)(Kt + (i * 16 + l16) * 72 + ko);
#pragma unroll
        for (int jj = 0; jj < 2; jj++)
            b[jj] = *(const short8*)(Vt + (w * 32 + jj * 16 + l16) * 72 + ko);
#pragma unroll
        for (int i = 0; i < 4; i++)
#pragma unroll
            for (int jj = 0; jj < 2; jj++)
                acc[i][jj] = __builtin_amdgcn_mfma_f32_16x16x32_bf16(a[i], b[jj], acc[i][jj], 0, 0, 0);
    }
#pragma unroll
    for (int i = 0; i < 4; i++)
#pragma unroll
        for (int jj = 0; jj < 2; jj++)
#pragma unroll
            for (int r2 = 0; r2 < 4; r2++) {
                int f = i * 16 + quad * 4 + r2;
                int d = w * 32 + jj * 16 + l16;
                KV_A[((size_t)chunk * 64 + f) * 1024 + p * 128 + d] = f2b(acc[i][jj][r2]);
            }
}

// ---------------------------------------------------------------------------
// Phase B1: exclusive prefix over 64 chunks per batch of KV states (bf16 in,
// fp32 accum, bf16 out). Grid: 1024 blocks (b*256 + f*4 + dseg), 256 threads.
// ---------------------------------------------------------------------------
__global__ __launch_bounds__(256) void eel_kv_prefix(
    const uint16_t* __restrict__ KV_A, uint16_t* __restrict__ KV_P)
{
    int bi = blockIdx.x;
    int b = bi >> 8, rem = bi & 255;
    int f = rem >> 2;
    int d = (rem & 3) * 256 + threadIdx.x;
    float acc = 0.f;
    for (int cc = 0; cc < 64; cc++) {
        size_t idx = (((size_t)(b * 64 + cc)) * 64 + f) * 1024 + d;
        KV_P[idx] = f2b(acc);
        acc += b2f(KV_A[idx]);
    }
}

// Phase B2: exclusive prefix of Ks over chunks. Grid 4 x 64 threads.
__global__ void eel_ks_prefix(const float* __restrict__ KsA, float* __restrict__ KsP)
{
    int b = blockIdx.x, f = threadIdx.x;
    float acc = 0.f;
    for (int cc = 0; cc < 64; cc++) {
        int idx = (b * 64 + cc) * 64 + f;
        KsP[idx] = acc;
        acc += KsA[idx];
    }
}

// ---------------------------------------------------------------------------
// Phase C (R6: MFMA): per (chunk, d-panel) attn[n,d] =
//   (Q[n,f].KV_P[f,d] + S[n,m].V[m,d]) / den_full[n].
// A-operands Q [n][f] and S [n][m] are native row-major (vector staged).
// B-operands KV_P^T [d][f] and V^T [d][m] transpose-staged (pad-72 rows).
// 4 waves, wave w owns d-range w*32..w*32+31; acc[4 n-tiles][2 d-tiles].
// ---------------------------------------------------------------------------
__global__ __launch_bounds__(256) void eel_attn_out(
    const uint16_t* __restrict__ QKV,
    const uint16_t* __restrict__ Sg,
    const float* __restrict__ den,
    const float* __restrict__ KsP,
    const uint16_t* __restrict__ KV_P,
    uint16_t* __restrict__ attn)    // [16384][1024] bf16
{
    int bi = blockIdx.x;
    int chunk = bi >> 3, p = bi & 7;
    int tid = threadIdx.x;
    int tok0 = chunk * 64;
    __shared__ uint16_t Qs[64 * 72];    // [n][f] native
    __shared__ uint16_t Ss[64 * 72];    // [n][m] native
    __shared__ uint16_t KVt[128 * 72];  // [d][f] transposed
    __shared__ uint16_t Vt[128 * 72];   // [d][m] transposed
    __shared__ float dfull[64];
    {
        int n = tid >> 2, seg = (tid & 3) * 16;
        const uint16_t* qsrc = QKV + (size_t)(tok0 + n) * 1152 + seg;
        *(short8*)(Qs + n * 72 + seg)     = *(const short8*)(qsrc);
        *(short8*)(Qs + n * 72 + seg + 8) = *(const short8*)(qsrc + 8);
        const uint16_t* ssrc = Sg + (size_t)(tok0 + n) * 64 + seg;
        *(short8*)(Ss + n * 72 + seg)     = *(const short8*)(ssrc);
        *(short8*)(Ss + n * 72 + seg + 8) = *(const short8*)(ssrc + 8);
    }
#pragma unroll
    for (int it = 0; it < 2; it++) {
        int s = it * 256 + tid;
        int r = s >> 3, d0 = (s & 7) * 16;   // r = f (KV_P) / m (V) source row
        const uint16_t* kvsrc = KV_P + ((size_t)(chunk * 64 + r)) * 1024 + p * 128 + d0;
        short8 k0 = *(const short8*)(kvsrc);
        short8 k1 = *(const short8*)(kvsrc + 8);
        const uint16_t* vsrc = QKV + (size_t)(tok0 + r) * 1152 + 128 + p * 128 + d0;
        short8 v0 = *(const short8*)(vsrc);
        short8 v1 = *(const short8*)(vsrc + 8);
#pragma unroll
        for (int j = 0; j < 8; j++) {
            KVt[(d0 + j) * 72 + r]     = (unsigned short)k0[j];
            KVt[(d0 + 8 + j) * 72 + r] = (unsigned short)k1[j];
            Vt[(d0 + j) * 72 + r]      = (unsigned short)v0[j];
            Vt[(d0 + 8 + j) * 72 + r]  = (unsigned short)v1[j];
        }
    }
    __syncthreads();
    if (tid < 64) {
        float s = 0.f;
#pragma unroll
        for (int f = 0; f < 64; f++)
            s += b2f(Qs[tid * 72 + f]) * KsP[chunk * 64 + f];
        dfull[tid] = s + den[tok0 + tid] + 1e-6f;
    }
    __syncthreads();
    int lane = tid & 63, w = tid >> 6;
    int quad = lane >> 4, l16 = lane & 15;
    floatx4 acc[4][2] = {};
#pragma unroll
    for (int ks = 0; ks < 2; ks++) {
        int ko = ks * 32 + quad * 8;
        short8 a[4], b[2];
#pragma unroll
        for (int i = 0; i < 4; i++)
            a[i] = *(const short8*)(Qs + (i * 16 + l16) * 72 + ko);
#pragma unroll
        for (int jj = 0; jj < 2; jj++)
            b[jj] = *(const short8*)(KVt + (w * 32 + jj * 16 + l16) * 72 + ko);
#pragma unroll
        for (int i = 0; i < 4; i++)
#pragma unroll
            for (int jj = 0; jj < 2; jj++)
                acc[i][jj] = __builtin_amdgcn_mfma_f32_16x16x32_bf16(a[i], b[jj], acc[i][jj], 0, 0, 0);
    }
#pragma unroll
    for (int ks = 0; ks < 2; ks++) {
        int ko = ks * 32 + quad * 8;
        short8 a[4], b[2];
#pragma unroll
        for (int i = 0; i < 4; i++)
            a[i] = *(const short8*)(Ss + (i * 16 + l16) * 72 + ko);
#pragma unroll
        for (int jj = 0; jj < 2; jj++)
            b[jj] = *(const short8*)(Vt + (w * 32 + jj * 16 + l16) * 72 + ko);
#pragma unroll
        for (int i = 0; i < 4; i++)
#pragma unroll
            for (int jj = 0; jj < 2; jj++)
                acc[i][jj] = __builtin_amdgcn_mfma_f32_16x16x32_bf16(a[i], b[jj], acc[i][jj], 0, 0, 0);
    }
#pragma unroll
    for (int i = 0; i < 4; i++)
#pragma unroll
        for (int r2 = 0; r2 < 4; r2++) {
            int n = i * 16 + quad * 4 + r2;
            float rinv = 1.0f / dfull[n];
#pragma unroll
            for (int jj = 0; jj < 2; jj++) {
                int d = w * 32 + jj * 16 + l16;
                attn[(size_t)(tok0 + n) * 1024 + p * 128 + d] = f2b(acc[i][jj][r2] * rinv);
            }
        }
}

// ---------------------------------------------------------------------------
// Host launcher
// ---------------------------------------------------------------------------
extern "C" void kernel_launch(void* const* d_in, const int* in_sizes, int n_in,
                              void* d_out, int out_size, void* d_ws, size_t ws_size,
                              hipStream_t stream)
{
    (void)in_sizes; (void)n_in; (void)out_size; (void)ws_size;
    const float* x     = (const float*)d_in[0];
    const float* ln1w  = (const float*)d_in[1];
    const float* ln1b  = (const float*)d_in[2];
    const float* qw    = (const float*)d_in[3];
    const float* qb    = (const float*)d_in[4];
    const float* kw    = (const float*)d_in[5];
    const float* kb    = (const float*)d_in[6];
    const float* vw    = (const float*)d_in[7];
    const float* vb    = (const float*)d_in[8];
    const float* ow    = (const float*)d_in[9];
    const float* ob    = (const float*)d_in[10];
    const float* ln2w  = (const float*)d_in[11];
    const float* ln2b  = (const float*)d_in[12];
    const float* f1w   = (const float*)d_in[13];
    const float* f1b   = (const float*)d_in[14];
    const float* f2w   = (const float*)d_in[15];
    const float* f2bs  = (const float*)d_in[16];
    float* out = (float*)d_out;
    char* ws = (char*)d_ws;

    // workspace layout (bytes)
    const size_t o_Wqkv = 0;                              // 1152*1024*2
    const size_t o_Wo   = o_Wqkv + 2359296;               // 1024*1024*2
    const size_t o_W1   = o_Wo   + 2097152;               // 4096*1024*2
    const size_t o_W2   = o_W1   + 8388608;               // 1024*4096*2
    const size_t o_bqkv = o_W2   + 8388608;               // 1152*4
    const size_t O_XN   = 21238272;   // x_norm bf16 33554432 (later: attn)
    const size_t O_QKV  = 54792704;   // QKV bf16 37748736    (later: h_norm)
    const size_t O_S    = 92541440;   // S bf16 2097152
    const size_t O_DEN  = 94638592;   // den fp32 65536
    const size_t O_KSA  = 94704128;   // KsA fp32 65536
    const size_t O_KSP  = 94769664;   // KsP fp32 65536
    const size_t O_KVA  = 94835200;   // KV_A bf16 33.5MB (later: h-strip bf16 67MB)
    const size_t O_KVP  = 161944064;  // KV_P bf16 33554432

    uint16_t* Wqkv  = (uint16_t*)(ws + o_Wqkv);
    uint16_t* Wo    = (uint16_t*)(ws + o_Wo);
    uint16_t* W1    = (uint16_t*)(ws + o_W1);
    uint16_t* W2    = (uint16_t*)(ws + o_W2);
    float*    bqkv  = (float*)(ws + o_bqkv);
    uint16_t* xn    = (uint16_t*)(ws + O_XN);
    uint16_t* attn  = (uint16_t*)(ws + O_XN);   // alias: x_norm dead after QKV GEMM
    uint16_t* QKV   = (uint16_t*)(ws + O_QKV);
    uint16_t* hnorm = (uint16_t*)(ws + O_QKV);  // alias: QKV dead after phase C
    uint16_t* Sg    = (uint16_t*)(ws + O_S);
    float*    den   = (float*)(ws + O_DEN);
    float*    KsA   = (float*)(ws + O_KSA);
    float*    KsP   = (float*)(ws + O_KSP);
    uint16_t* KV_A  = (uint16_t*)(ws + O_KVA);
    uint16_t* hbuf  = (uint16_t*)(ws + O_KVA);  // alias: KV_A dead after prefix
    uint16_t* KV_P  = (uint16_t*)(ws + O_KVP);

    // 1. weight prep
    eel_prep<<<4096, 256, 0, stream>>>(qw, kw, vw, ow, f1w, f2w, qb, kb, vb,
                                       Wqkv, Wo, W1, W2, bqkv);
    // 2. LN1: x -> x_norm (bf16)
    eel_ln<<<16384, 256, 0, stream>>>(x, ln1w, ln1b, xn);
    // 3. QKV projection: [16384,1024] @ [1152,1024]^T -> QKV bf16, elu+1 on Q,K
    eel_gemm<<<dim3(128, 9), 256, 0, stream>>>(xn, 1024, Wqkv, 1024, 1024,
                                               bqkv, nullptr, QKV, nullptr, 1152, 0);
    // 4. phase A1: S, den_intra, Ks per chunk
    eel_attn_s<<<256, 256, 0, stream>>>(QKV, Sg, den, KsA);
    // 5. phase A2: per-chunk KV states (bf16) -- MFMA
    eel_attn_kv<<<2048, 256, 0, stream>>>(QKV, KV_A);
    // 6. phase B1: KV prefix (exclusive), bf16 in/out, fp32 accum
    eel_kv_prefix<<<1024, 256, 0, stream>>>(KV_A, KV_P);
    // 7. phase B2: Ks prefix
    eel_ks_prefix<<<4, 64, 0, stream>>>(KsA, KsP);
    // 8. phase C: attention output -> attn bf16 (aliases x_norm) -- MFMA
    eel_attn_out<<<2048, 256, 0, stream>>>(QKV, Sg, den, KsP, KV_P, attn);
    // 9. O-proj + residual: attn @ Wo^T + ob + x -> d_out (fp32, y1)
    eel_gemm<<<dim3(128, 8), 256, 0, stream>>>(attn, 1024, Wo, 1024, 1024,
                                               ob, x, nullptr, out, 1024, 1);
    // 10. LN2: d_out -> h_norm bf16 (aliases QKV)
    eel_ln<<<16384, 256, 0, stream>>>(out, ln2w, ln2b, hnorm);
    // 11-14. FFN as two N-strips of 2048 over full M=16384:
    //   FFN1 strip: hnorm @ W1[strip]^T -> gelu -> h-strip bf16 [16384,2048]
    //   FFN2 strip: h-strip @ W2[:,strip]^T (+f2b on strip 0) + out -> out
    for (int strip = 0; strip < 2; strip++) {
        size_t noff = (size_t)strip * 2048;
        eel_gemm<<<dim3(128, 16), 256, 0, stream>>>(hnorm, 1024, W1 + noff * 1024, 1024, 1024,
                                                    f1b + noff, nullptr, hbuf, nullptr, 2048, 2);
        eel_gemm<<<dim3(128, 8), 256, 0, stream>>>(hbuf, 2048, W2 + noff, 4096, 2048,
                                                   strip == 0 ? f2bs : nullptr, out, nullptr,
                                                   out, 1024, 1);
    }
}